// Round 4
// baseline (558.775 us; speedup 1.0000x reference)
//
#include <hip/hip_runtime.h>
#include <hip/hip_bf16.h>
#include <math.h>

// Sizes: B=16, N=64, nE=128, H=128, LAT=128, NS=64, NV=32, INV=96, D_NODE=160
#define SQRT3F 1.7320508075688772f
#define ALPHAF 0.10206207261596577f  // 1/sqrt(96)
#define PIF 3.14159265358979323846f

__device__ __forceinline__ float silu_f(float x) {
  return x / (1.0f + __expf(-x));
}
__device__ __forceinline__ float sigmoid_f(float x) {
  return 1.0f / (1.0f + __expf(-x));
}

// ---------------------------------------------------------------------------
// K0: per-node prep. grid=1024 (g = b*64+n), block=128.
// ---------------------------------------------------------------------------
__global__ void k_prep(const float* __restrict__ hf, const int* __restrict__ z,
                       const float* __restrict__ pos, const float* __restrict__ z_emb,
                       const float* __restrict__ vwW0, const float* __restrict__ vwb0,
                       const float* __restrict__ vwW1, const float* __restrict__ vwb1,
                       const float* __restrict__ scW0,
                       float* __restrict__ hidden, float* __restrict__ Pn,
                       float* __restrict__ Pa, float* __restrict__ xvu,
                       float* __restrict__ y1cw) {
  const int g = blockIdx.x;
  const int b = g >> 6, n = g & 63;
  const int t = threadIdx.x;

  __shared__ float vin[64];
  __shared__ float invn[96];
  __shared__ float h0[128];
  __shared__ float uS[3];
  __shared__ float rS;

  if (t == 0) {
    float px = pos[g * 3 + 0] - pos[(b * 64) * 3 + 0];
    float py = pos[g * 3 + 1] - pos[(b * 64) * 3 + 1];
    float pz = pos[g * 3 + 2] - pos[(b * 64) * 3 + 2];
    float r = sqrtf(px * px + py * py + pz * pz + 1e-12f);
    float rm = fmaxf(r, 1e-8f);
    uS[0] = px / rm; uS[1] = py / rm; uS[2] = pz / rm;
    rS = r;
  }
  __syncthreads();
  const float r = rS;

  if (t < 32) {
    int zi = z[g];
    vin[t] = z_emb[zi * 32 + t];
    const float delta = 6.0f / 31.0f;
    const float gamma = 1.0f / (delta * delta + 1e-12f);
    float rc = fminf(r, 6.0f);
    float d = rc - (float)t * delta;
    vin[32 + t] = __expf(-gamma * d * d);
  }
  if (t < 96) {
    if (t < 64) {
      invn[t] = hf[g * 160 + t];
    } else {
      int o = t - 64;
      float v0 = hf[g * 160 + 64 + o * 3 + 0];
      float v1 = hf[g * 160 + 64 + o * 3 + 1];
      float v2 = hf[g * 160 + 64 + o * 3 + 2];
      invn[t] = sqrtf((v0 * v0 + v1 * v1 + v2 * v2) * (1.0f / 3.0f) + 1e-8f);
    }
  }
  __syncthreads();

  {
    float a = vwb0[t];
    #pragma unroll 8
    for (int k = 0; k < 64; ++k) a = fmaf(vin[k], vwW0[k * 128 + t], a);
    h0[t] = silu_f(a);
  }
  __syncthreads();
  {
    float a = vwb1[t];
    #pragma unroll 8
    for (int k = 0; k < 128; ++k) a = fmaf(h0[k], vwW1[k * 128 + t], a);
    hidden[g * 128 + t] = silu_f(a);
  }
  {
    float p = 0.0f;
    #pragma unroll 8
    for (int k = 0; k < 96; ++k) p = fmaf(invn[k], scW0[(96 + k) * 128 + t], p);
    #pragma unroll 8
    for (int k = 0; k < 64; ++k) p = fmaf(vin[k], scW0[(192 + k) * 128 + t], p);
    Pn[g * 128 + t] = p;
  }
  if (n == 0) {
    float p = 0.0f;
    #pragma unroll 8
    for (int k = 0; k < 96; ++k) p = fmaf(invn[k], scW0[k * 128 + t], p);
    Pa[b * 128 + t] = p;
  }
  if (t < 32) {
    float a = hf[g * 160 + 64 + t * 3 + 0] * uS[0]
            + hf[g * 160 + 64 + t * 3 + 1] * uS[1]
            + hf[g * 160 + 64 + t * 3 + 2] * uS[2];
    xvu[g * 32 + t] = a;
  }
  if (t == 0) {
    float cw = 0.0f;
    if (r <= 6.0f && n != 0) cw = 0.5f * (cosf(PIF * r * (1.0f / 6.0f)) + 1.0f);
    y1cw[g * 4 + 0] = SQRT3F * uS[0];
    y1cw[g * 4 + 1] = SQRT3F * uS[1];
    y1cw[g * 4 + 2] = SQRT3F * uS[2];
    y1cw[g * 4 + 3] = cw;
  }
}

// ---------------------------------------------------------------------------
// KPe: Pe[e][t] = sc_b0[t] + e_feat[e]@We. grid=128, block=128.
// ---------------------------------------------------------------------------
__global__ void k_pe(const float* __restrict__ e_feat, const float* __restrict__ scW0,
                     const float* __restrict__ scb0, float* __restrict__ Pe) {
  const int e = blockIdx.x;
  const int t = threadIdx.x;
  float a = scb0[t];
  #pragma unroll
  for (int k = 0; k < 16; ++k) a = fmaf(e_feat[e * 16 + k], scW0[(256 + k) * 128 + t], a);
  Pe[e * 128 + t] = a;
}

// ---------------------------------------------------------------------------
// K2 v4: fused TP-weight GEMM + contraction.
// grid = (64 node-tiles of 16, 9 column-chunks of 1024), block = 256.
// Each thread owns 4 CONSECUTIVE cols, loaded as float4: 4 vmem instrs/kc
// instead of 16 (R2/R3 both issued the same 1.18M wave-loads and both ran
// 127us -> vmem-instruction-throughput-bound theory). acc = float4[16] = 64
// VGPRs + 32 double-buffer -> fits 4 waves/SIMD.
// ---------------------------------------------------------------------------
#define TP_NT 16
__global__ void __launch_bounds__(256, 4) k_tp(
    const float* __restrict__ hidden, const float* __restrict__ W2,
    const float* __restrict__ b2, const float* __restrict__ hf,
    const float* __restrict__ xvu, const float* __restrict__ y1cw,
    float* __restrict__ values) {
  const int tile = blockIdx.x;
  const int chunk = blockIdx.y;
  const int tid = threadIdx.x;
  const int g0 = tile * TP_NT;

  __shared__ float4 hid4[TP_NT][32];
  __shared__ float xsL[TP_NT][64];
  __shared__ float xvL[TP_NT][96];
  __shared__ float xvuL[TP_NT][32];
  __shared__ float4 y1L[TP_NT];
  __shared__ float valsL[TP_NT][160];
  __shared__ float svL[TP_NT][32];

  for (int idx = tid; idx < TP_NT * 128; idx += 256) {
    int nn = idx >> 7, k = idx & 127;
    ((float*)&hid4[nn][0])[k] = hidden[(g0 + nn) * 128 + k];
  }
  for (int idx = tid; idx < TP_NT * 64; idx += 256) {
    int nn = idx >> 6, k = idx & 63;
    xsL[nn][k] = hf[(g0 + nn) * 160 + k];
  }
  for (int idx = tid; idx < TP_NT * 96; idx += 256) {
    int nn = idx / 96, k = idx - nn * 96;
    xvL[nn][k] = hf[(g0 + nn) * 160 + 64 + k];
  }
  for (int idx = tid; idx < TP_NT * 32; idx += 256) {
    int nn = idx >> 5, k = idx & 31;
    xvuL[nn][k] = xvu[(g0 + nn) * 32 + k];
    svL[nn][k] = 0.0f;
  }
  if (tid < TP_NT) y1L[tid] = ((const float4*)y1cw)[g0 + tid];
  for (int idx = tid; idx < TP_NT * 160; idx += 256) {
    valsL[idx / 160][idx % 160] = 0.0f;
  }
  __syncthreads();

  float4 acc4[TP_NT];
  #pragma unroll
  for (int nn = 0; nn < TP_NT; ++nn) acc4[nn] = make_float4(0.f, 0.f, 0.f, 0.f);

  const int j0 = chunk * 1024 + (tid << 2);   // 4 consecutive cols
  const float* wbase = W2 + j0;

  float4 wcur[4], wnxt[4];
  #pragma unroll
  for (int q = 0; q < 4; ++q)
    wcur[q] = *(const float4*)(wbase + (size_t)q * 9216);

  #pragma unroll 2
  for (int kc = 0; kc < 32; ++kc) {
    if (kc < 31) {
      const float* wp = wbase + (size_t)((kc + 1) * 4) * 9216;
      #pragma unroll
      for (int q = 0; q < 4; ++q)
        wnxt[q] = *(const float4*)(wp + (size_t)q * 9216);
    }
    #pragma unroll
    for (int nn = 0; nn < TP_NT; ++nn) {
      float4 h = hid4[nn][kc];
      float4 a = acc4[nn];
      a.x = fmaf(h.x, wcur[0].x, fmaf(h.y, wcur[1].x, fmaf(h.z, wcur[2].x, fmaf(h.w, wcur[3].x, a.x))));
      a.y = fmaf(h.x, wcur[0].y, fmaf(h.y, wcur[1].y, fmaf(h.z, wcur[2].y, fmaf(h.w, wcur[3].y, a.y))));
      a.z = fmaf(h.x, wcur[0].z, fmaf(h.y, wcur[1].z, fmaf(h.z, wcur[2].z, fmaf(h.w, wcur[3].z, a.z))));
      a.w = fmaf(h.x, wcur[0].w, fmaf(h.y, wcur[1].w, fmaf(h.z, wcur[2].w, fmaf(h.w, wcur[3].w, a.w))));
      acc4[nn] = a;
    }
    #pragma unroll
    for (int q = 0; q < 4; ++q) wcur[q] = wnxt[q];
  }

  // contraction: thread's 4 cols are consecutive; segment boundaries
  // (4096/6144/7168) are 4-aligned so all 4 stay in one segment; i is the
  // same for all 4 (boundaries of i-blocks are 32/64-aligned).
  {
    const int jb = j0;
    const float4 bias4 = *(const float4*)(b2 + jb);
    const float bias[4] = {bias4.x, bias4.y, bias4.z, bias4.w};
    #pragma unroll
    for (int c = 0; c < 4; ++c) {
      const int j = jb + c;
      const float tpacc_bias = bias[c];
      float tpv[TP_NT];
      #pragma unroll
      for (int nn = 0; nn < TP_NT; ++nn)
        tpv[nn] = ((const float*)&acc4[nn])[c] + tpacc_bias;
      if (j < 4096) {
        int i = j >> 6, o = j & 63;
        #pragma unroll
        for (int nn = 0; nn < TP_NT; ++nn)
          atomicAdd(&valsL[nn][o], xsL[nn][i] * tpv[nn]);
      } else if (j < 6144) {
        int t2 = j - 4096; int i = t2 >> 5, o = t2 & 31;
        #pragma unroll
        for (int nn = 0; nn < TP_NT; ++nn)
          atomicAdd(&svL[nn][o], xsL[nn][i] * tpv[nn]);
      } else if (j < 7168) {
        int t2 = j - 6144; int i = t2 >> 5, o = t2 & 31;
        #pragma unroll
        for (int nn = 0; nn < TP_NT; ++nn) {
          float tp = tpv[nn];
          atomicAdd(&valsL[nn][64 + o * 3 + 0], xvL[nn][i * 3 + 0] * tp);
          atomicAdd(&valsL[nn][64 + o * 3 + 1], xvL[nn][i * 3 + 1] * tp);
          atomicAdd(&valsL[nn][64 + o * 3 + 2], xvL[nn][i * 3 + 2] * tp);
        }
      } else {
        int t2 = j - 7168; int i = t2 >> 6, o = t2 & 63;
        #pragma unroll
        for (int nn = 0; nn < TP_NT; ++nn)
          atomicAdd(&valsL[nn][o], xvuL[nn][i] * tpv[nn]);
      }
    }
  }
  __syncthreads();

  for (int idx = tid; idx < TP_NT * 160; idx += 256) {
    int nn = idx / 160, d = idx - nn * 160;
    float v = valsL[nn][d];
    if (d >= 64) {
      int dd = d - 64, o = dd / 3, cc = dd - o * 3;
      float4 y = y1L[nn];
      float yc = (cc == 0) ? y.x : ((cc == 1) ? y.y : y.z);
      v = fmaf(svL[nn][o], yc, v);
    }
    atomicAdd(&values[(g0 + nn) * 160 + d], ALPHAF * v);
  }
}

// ---------------------------------------------------------------------------
// K3: gate MLP + aggregation per (b,e). grid=2048, block=256.
// Barrier-free K-loop with explicit register double-buffer for W1 rows.
// ---------------------------------------------------------------------------
__global__ void __launch_bounds__(256) k_gate_agg(
    const float* __restrict__ Pa, const float* __restrict__ Pe,
    const float* __restrict__ Pn, const float* __restrict__ W1,
    const float* __restrict__ b1, const float* __restrict__ W2v,
    const float* __restrict__ b2s, const float* __restrict__ y1cw,
    const float* __restrict__ values, float* __restrict__ inv_agg) {
  const int bid = blockIdx.x;
  const int b = bid >> 7, e = bid & 127;
  const int tid = threadIdx.x;

  __shared__ float A[64][129];
  __shared__ float Prow[128];
  __shared__ float gpart[64][17];
  __shared__ float gateL[64];
  __shared__ float aggL[160];
  __shared__ float normS;

  if (tid < 128) Prow[tid] = Pa[b * 128 + tid] + Pe[e * 128 + tid];
  __syncthreads();
  {
    const float* pn = Pn + (size_t)b * 64 * 128;
    for (int idx = tid; idx < 8192; idx += 256) {
      int n = idx >> 7, k = idx & 127;
      A[n][k] = silu_f(pn[idx] + Prow[k]);
    }
  }
  __syncthreads();

  const int rowg = tid >> 4, colg = tid & 15;
  const int r4 = rowg * 4, c8 = colg * 8;

  float acc[4][8];
  #pragma unroll
  for (int i = 0; i < 4; ++i)
    #pragma unroll
    for (int jj = 0; jj < 8; ++jj) acc[i][jj] = 0.0f;

  const float* wptr = W1 + c8;
  float4 w0c = *(const float4*)(wptr);
  float4 w1c = *(const float4*)(wptr + 4);
  #pragma unroll 2
  for (int k = 0; k < 128; ++k) {
    float4 w0n, w1n;
    if (k < 127) {
      w0n = *(const float4*)(wptr + (k + 1) * 128);
      w1n = *(const float4*)(wptr + (k + 1) * 128 + 4);
    }
    float av0 = A[r4 + 0][k];
    float av1 = A[r4 + 1][k];
    float av2 = A[r4 + 2][k];
    float av3 = A[r4 + 3][k];
    float wv[8] = {w0c.x, w0c.y, w0c.z, w0c.w, w1c.x, w1c.y, w1c.z, w1c.w};
    #pragma unroll
    for (int jj = 0; jj < 8; ++jj) {
      acc[0][jj] = fmaf(av0, wv[jj], acc[0][jj]);
      acc[1][jj] = fmaf(av1, wv[jj], acc[1][jj]);
      acc[2][jj] = fmaf(av2, wv[jj], acc[2][jj]);
      acc[3][jj] = fmaf(av3, wv[jj], acc[3][jj]);
    }
    w0c = w0n; w1c = w1n;
  }

  float p[4] = {0.0f, 0.0f, 0.0f, 0.0f};
  #pragma unroll
  for (int jj = 0; jj < 8; ++jj) {
    float bb = b1[c8 + jj];
    float wg = W2v[c8 + jj];
    #pragma unroll
    for (int i = 0; i < 4; ++i) {
      float h = silu_f(acc[i][jj] + bb);
      p[i] = fmaf(h, wg, p[i]);
    }
  }
  #pragma unroll
  for (int i = 0; i < 4; ++i) gpart[r4 + i][colg] = p[i];
  __syncthreads();

  if (tid < 64) {
    float s = 0.0f;
    #pragma unroll
    for (int cg = 0; cg < 16; ++cg) s += gpart[tid][cg];
    float gv = sigmoid_f(s + b2s[0]);
    gv *= y1cw[(b * 64 + tid) * 4 + 3];
    gateL[tid] = gv;
    float t = gv;
    #pragma unroll
    for (int off = 32; off > 0; off >>= 1) t += __shfl_down(t, off);
    if (tid == 0) normS = fmaxf(t, 1e-8f);
  }
  __syncthreads();

  if (tid < 160) {
    float a = 0.0f;
    const float* vp = values + (size_t)b * 64 * 160 + tid;
    #pragma unroll 4
    for (int n = 0; n < 64; ++n) a = fmaf(gateL[n], vp[n * 160], a);
    aggL[tid] = a / normS;
  }
  __syncthreads();
  if (tid < 96) {
    float rv;
    if (tid < 64) {
      rv = aggL[tid];
    } else {
      int o = tid - 64;
      float a0 = aggL[64 + o * 3 + 0];
      float a1 = aggL[64 + o * 3 + 1];
      float a2 = aggL[64 + o * 3 + 2];
      rv = sqrtf((a0 * a0 + a1 * a1 + a2 * a2) * (1.0f / 3.0f) + 1e-8f);
    }
    inv_agg[bid * 96 + tid] = rv;
  }
}

// ---------------------------------------------------------------------------
// K4: MLP layer Y = act(X@W + b). 32-row tiles -> 64 blocks. K in {96,128}.
// ---------------------------------------------------------------------------
__global__ void __launch_bounds__(256) k_mlp(
    const float* __restrict__ X, const float* __restrict__ W,
    const float* __restrict__ bias, float* __restrict__ Y,
    int K, int act) {
  const int r0 = blockIdx.x * 32;
  const int tid = threadIdx.x;

  __shared__ float A[32][129];

  for (int idx = tid; idx < 32 * K; idx += 256) {
    int n = idx / K, k = idx - n * K;
    A[n][k] = X[(size_t)(r0 + n) * K + k];
  }
  __syncthreads();

  const int rowg = tid >> 4, colg = tid & 15;
  const int r2 = rowg * 2, c8 = colg * 8;

  float acc[2][8];
  #pragma unroll
  for (int i = 0; i < 2; ++i)
    #pragma unroll
    for (int jj = 0; jj < 8; ++jj) acc[i][jj] = 0.0f;

  const float* wptr = W + c8;
  #pragma unroll 4
  for (int k = 0; k < K; ++k) {
    float4 w0 = *(const float4*)(wptr + k * 128);
    float4 w1v = *(const float4*)(wptr + k * 128 + 4);
    float av0 = A[r2 + 0][k];
    float av1 = A[r2 + 1][k];
    float wv[8] = {w0.x, w0.y, w0.z, w0.w, w1v.x, w1v.y, w1v.z, w1v.w};
    #pragma unroll
    for (int jj = 0; jj < 8; ++jj) {
      acc[0][jj] = fmaf(av0, wv[jj], acc[0][jj]);
      acc[1][jj] = fmaf(av1, wv[jj], acc[1][jj]);
    }
  }

  #pragma unroll
  for (int jj = 0; jj < 8; ++jj) {
    float bb = bias[c8 + jj];
    #pragma unroll
    for (int i = 0; i < 2; ++i) {
      float v = acc[i][jj] + bb;
      if (act) v = silu_f(v);
      Y[(size_t)(r0 + r2 + i) * 128 + c8 + jj] = v;
    }
  }
}

// ---------------------------------------------------------------------------
extern "C" void kernel_launch(void* const* d_in, const int* in_sizes, int n_in,
                              void* d_out, int out_size, void* d_ws, size_t ws_size,
                              hipStream_t stream) {
  const float* hf    = (const float*)d_in[0];
  const int*   z     = (const int*)  d_in[1];
  const float* pos   = (const float*)d_in[2];
  const float* e_feat= (const float*)d_in[4];
  const float* z_emb = (const float*)d_in[5];
  const float* vwW0  = (const float*)d_in[6];
  const float* vwb0  = (const float*)d_in[7];
  const float* vwW1  = (const float*)d_in[8];
  const float* vwb1  = (const float*)d_in[9];
  const float* vwW2  = (const float*)d_in[10];
  const float* vwb2  = (const float*)d_in[11];
  const float* scW0  = (const float*)d_in[12];
  const float* scb0  = (const float*)d_in[13];
  const float* scW1  = (const float*)d_in[14];
  const float* scb1  = (const float*)d_in[15];
  const float* scW2  = (const float*)d_in[16];
  const float* scb2  = (const float*)d_in[17];
  const float* oW0   = (const float*)d_in[18];
  const float* ob0   = (const float*)d_in[19];
  const float* oW1   = (const float*)d_in[20];
  const float* ob1   = (const float*)d_in[21];
  const float* oW2   = (const float*)d_in[22];
  const float* ob2   = (const float*)d_in[23];
  float* out = (float*)d_out;

  float* ws = (float*)d_ws;
  float* hidden = ws;                 // 1024*128
  float* Pn     = hidden + 131072;    // 1024*128
  float* Pa     = Pn + 131072;        // 16*128
  float* Pe     = Pa + 2048;          // 128*128
  float* xvu    = Pe + 16384;         // 1024*32
  float* y1cw   = xvu + 32768;        // 1024*4
  float* values = y1cw + 4096;        // 1024*160
  float* invagg = values + 163840;    // 2048*96
  float* H1     = invagg + 196608;    // 2048*128
  float* H2     = H1 + 262144;        // 2048*128

  hipMemsetAsync(values, 0, 163840 * sizeof(float), stream);

  k_prep<<<1024, 128, 0, stream>>>(hf, z, pos, z_emb, vwW0, vwb0, vwW1, vwb1,
                                   scW0, hidden, Pn, Pa, xvu, y1cw);
  k_pe<<<128, 128, 0, stream>>>(e_feat, scW0, scb0, Pe);
  k_tp<<<dim3(64, 9), 256, 0, stream>>>(hidden, vwW2, vwb2, hf, xvu, y1cw, values);
  k_gate_agg<<<2048, 256, 0, stream>>>(Pa, Pe, Pn, scW1, scb1, scW2, scb2,
                                       y1cw, values, invagg);
  k_mlp<<<64, 256, 0, stream>>>(invagg, oW0, ob0, H1, 96, 1);
  k_mlp<<<64, 256, 0, stream>>>(H1, oW1, ob1, H2, 128, 1);
  k_mlp<<<64, 256, 0, stream>>>(H2, oW2, ob2, out, 128, 0);
}

// Round 5
// 483.306 us; speedup vs baseline: 1.1562x; 1.1562x over previous
//
#include <hip/hip_runtime.h>
#include <hip/hip_bf16.h>
#include <math.h>

// Sizes: B=16, N=64, nE=128, H=128, LAT=128, NS=64, NV=32, INV=96, D_NODE=160
#define SQRT3F 1.7320508075688772f
#define ALPHAF 0.10206207261596577f  // 1/sqrt(96)
#define PIF 3.14159265358979323846f

__device__ __forceinline__ float silu_f(float x) {
  return x / (1.0f + __expf(-x));
}
__device__ __forceinline__ float sigmoid_f(float x) {
  return 1.0f / (1.0f + __expf(-x));
}

// ---------------------------------------------------------------------------
// K0 v2: per-node prep, 4 nodes per block. grid=256, block=128.
// Each weight load feeds 4 FMAs (one per node) -> 4x less L2 weight traffic
// and 4x more compute per load latency. Writes hiddenT[k][node] (transposed)
// for k_tp's coalesced A-staging.
// ---------------------------------------------------------------------------
__global__ void k_prep(const float* __restrict__ hf, const int* __restrict__ z,
                       const float* __restrict__ pos, const float* __restrict__ z_emb,
                       const float* __restrict__ vwW0, const float* __restrict__ vwb0,
                       const float* __restrict__ vwW1, const float* __restrict__ vwb1,
                       const float* __restrict__ scW0,
                       float* __restrict__ hiddenT, float* __restrict__ Pn,
                       float* __restrict__ Pa, float* __restrict__ xvu,
                       float* __restrict__ y1cw) {
  const int g0 = blockIdx.x * 4;          // 4 nodes per block
  const int b = g0 >> 6;
  const int t = threadIdx.x;              // 128

  __shared__ float vin[4][64];
  __shared__ float invn[4][96];
  __shared__ float h0[4][128];
  __shared__ float uS[4][3];
  __shared__ float rS[4];

  if (t < 4) {
    const int g = g0 + t;
    float px = pos[g * 3 + 0] - pos[(b * 64) * 3 + 0];
    float py = pos[g * 3 + 1] - pos[(b * 64) * 3 + 1];
    float pz = pos[g * 3 + 2] - pos[(b * 64) * 3 + 2];
    float r = sqrtf(px * px + py * py + pz * pz + 1e-12f);
    float rm = fmaxf(r, 1e-8f);
    uS[t][0] = px / rm; uS[t][1] = py / rm; uS[t][2] = pz / rm;
    rS[t] = r;
  }
  __syncthreads();

  if (t < 32) {
    const float delta = 6.0f / 31.0f;
    const float gamma = 1.0f / (delta * delta + 1e-12f);
    #pragma unroll
    for (int nn = 0; nn < 4; ++nn) {
      int zi = z[g0 + nn];
      vin[nn][t] = z_emb[zi * 32 + t];
      float rc = fminf(rS[nn], 6.0f);
      float d = rc - (float)t * delta;
      vin[nn][32 + t] = __expf(-gamma * d * d);
      // xvu
      float a = hf[(g0 + nn) * 160 + 64 + t * 3 + 0] * uS[nn][0]
              + hf[(g0 + nn) * 160 + 64 + t * 3 + 1] * uS[nn][1]
              + hf[(g0 + nn) * 160 + 64 + t * 3 + 2] * uS[nn][2];
      xvu[(g0 + nn) * 32 + t] = a;
    }
  }
  if (t < 96) {
    #pragma unroll
    for (int nn = 0; nn < 4; ++nn) {
      const int g = g0 + nn;
      if (t < 64) {
        invn[nn][t] = hf[g * 160 + t];
      } else {
        int o = t - 64;
        float v0 = hf[g * 160 + 64 + o * 3 + 0];
        float v1 = hf[g * 160 + 64 + o * 3 + 1];
        float v2 = hf[g * 160 + 64 + o * 3 + 2];
        invn[nn][t] = sqrtf((v0 * v0 + v1 * v1 + v2 * v2) * (1.0f / 3.0f) + 1e-8f);
      }
    }
  }
  if (t < 4) {
    const int n = (g0 + t) & 63;
    float r = rS[t];
    float cw = 0.0f;
    if (r <= 6.0f && n != 0) cw = 0.5f * (cosf(PIF * r * (1.0f / 6.0f)) + 1.0f);
    y1cw[(g0 + t) * 4 + 0] = SQRT3F * uS[t][0];
    y1cw[(g0 + t) * 4 + 1] = SQRT3F * uS[t][1];
    y1cw[(g0 + t) * 4 + 2] = SQRT3F * uS[t][2];
    y1cw[(g0 + t) * 4 + 3] = cw;
  }
  __syncthreads();

  // layer 1: 64 -> 128 (4 nodes share each weight load)
  {
    float a0 = vwb0[t], a1 = a0, a2 = a0, a3 = a0;
    #pragma unroll 8
    for (int k = 0; k < 64; ++k) {
      float w = vwW0[k * 128 + t];
      a0 = fmaf(vin[0][k], w, a0);
      a1 = fmaf(vin[1][k], w, a1);
      a2 = fmaf(vin[2][k], w, a2);
      a3 = fmaf(vin[3][k], w, a3);
    }
    h0[0][t] = silu_f(a0); h0[1][t] = silu_f(a1);
    h0[2][t] = silu_f(a2); h0[3][t] = silu_f(a3);
  }
  __syncthreads();
  // layer 2: 128 -> 128, write transposed hiddenT[k=t][node]
  {
    float a0 = vwb1[t], a1 = a0, a2 = a0, a3 = a0;
    #pragma unroll 8
    for (int k = 0; k < 128; ++k) {
      float w = vwW1[k * 128 + t];
      a0 = fmaf(h0[0][k], w, a0);
      a1 = fmaf(h0[1][k], w, a1);
      a2 = fmaf(h0[2][k], w, a2);
      a3 = fmaf(h0[3][k], w, a3);
    }
    hiddenT[t * 1024 + g0 + 0] = silu_f(a0);
    hiddenT[t * 1024 + g0 + 1] = silu_f(a1);
    hiddenT[t * 1024 + g0 + 2] = silu_f(a2);
    hiddenT[t * 1024 + g0 + 3] = silu_f(a3);
  }
  // Pn
  {
    float p0 = 0.f, p1 = 0.f, p2 = 0.f, p3 = 0.f;
    #pragma unroll 8
    for (int k = 0; k < 96; ++k) {
      float w = scW0[(96 + k) * 128 + t];
      p0 = fmaf(invn[0][k], w, p0);
      p1 = fmaf(invn[1][k], w, p1);
      p2 = fmaf(invn[2][k], w, p2);
      p3 = fmaf(invn[3][k], w, p3);
    }
    #pragma unroll 8
    for (int k = 0; k < 64; ++k) {
      float w = scW0[(192 + k) * 128 + t];
      p0 = fmaf(vin[0][k], w, p0);
      p1 = fmaf(vin[1][k], w, p1);
      p2 = fmaf(vin[2][k], w, p2);
      p3 = fmaf(vin[3][k], w, p3);
    }
    Pn[(g0 + 0) * 128 + t] = p0;
    Pn[(g0 + 1) * 128 + t] = p1;
    Pn[(g0 + 2) * 128 + t] = p2;
    Pn[(g0 + 3) * 128 + t] = p3;
  }
  if ((g0 & 63) == 0) {   // node 0 of batch b: inv_abs row
    float p = 0.0f;
    #pragma unroll 8
    for (int k = 0; k < 96; ++k) p = fmaf(invn[0][k], scW0[k * 128 + t], p);
    Pa[b * 128 + t] = p;
  }
}

// ---------------------------------------------------------------------------
// KPe: Pe[e][t] = sc_b0[t] + e_feat[e]@We. grid=128, block=128.
// ---------------------------------------------------------------------------
__global__ void k_pe(const float* __restrict__ e_feat, const float* __restrict__ scW0,
                     const float* __restrict__ scb0, float* __restrict__ Pe) {
  const int e = blockIdx.x;
  const int t = threadIdx.x;
  float a = scb0[t];
  #pragma unroll
  for (int k = 0; k < 16; ++k) a = fmaf(e_feat[e * 16 + k], scW0[(256 + k) * 128 + t], a);
  Pe[e * 128 + t] = a;
}

// ---------------------------------------------------------------------------
// K2 v5: LDS-tiled GEMM + fused contraction.
// grid = (16 node-tiles of 64, 36 col-chunks of 256), block = 256.
// Thread tile 8 nodes x 8 cols (acc[8][8], compile-time indices ONLY — R4's
// spill disaster came from address-indexing a register array).
// W2 and hiddenT slices staged to LDS, register-buffered pipeline:
// load slice k+1 -> compute slice k (512 FMA cover) -> ds_write -> barrier.
// ---------------------------------------------------------------------------
__global__ void __launch_bounds__(256, 2) k_tp(
    const float* __restrict__ hiddenT, const float* __restrict__ W2,
    const float* __restrict__ b2, const float* __restrict__ hf,
    const float* __restrict__ xvu, const float* __restrict__ y1cw,
    float* __restrict__ values) {
  const int g0 = blockIdx.x * 64;        // node tile
  const int chunk = blockIdx.y;          // 36 chunks of 256 cols
  const int C0 = chunk * 256;
  const int tid = threadIdx.x;

  __shared__ float Bs[2][8][260];        // W2 slice [kk][col], pad 260 (16B-ok)
  __shared__ float ATs[2][8][68];        // hiddenT slice [kk][node], pad 68
  __shared__ float valsS[64][160];
  __shared__ float svS[64][32];

  // zero accumult buffers
  for (int idx = tid; idx < 64 * 160; idx += 256) ((float*)valsS)[idx] = 0.0f;
  for (int idx = tid; idx < 64 * 32; idx += 256) ((float*)svS)[idx] = 0.0f;

  const int colg = tid & 31;             // 0..31
  const int rowg = tid >> 5;             // 0..7
  const int c8 = colg * 8;
  const int r8 = rowg * 8;

  // staging indices
  const int bk0 = tid >> 6;              // slot tid:     kk, c4
  const int bc0 = (tid & 63) * 4;
  const int bk1 = (tid + 256) >> 6;      // slot tid+256
  const int bc1 = ((tid + 256) & 63) * 4;
  const int ak = tid >> 4;               // slot tid (tid<128): kk, n4
  const int an = (tid & 15) * 4;

  // initial stage -> buf 0
  {
    float4 bv0 = *(const float4*)(W2 + (size_t)bk0 * 9216 + C0 + bc0);
    float4 bv1 = *(const float4*)(W2 + (size_t)bk1 * 9216 + C0 + bc1);
    *(float4*)&Bs[0][bk0][bc0] = bv0;
    *(float4*)&Bs[0][bk1][bc1] = bv1;
    if (tid < 128) {
      float4 av = *(const float4*)(hiddenT + (size_t)ak * 1024 + g0 + an);
      *(float4*)&ATs[0][ak][an] = av;
    }
  }
  __syncthreads();

  float acc[8][8];
  #pragma unroll
  for (int i = 0; i < 8; ++i)
    #pragma unroll
    for (int j = 0; j < 8; ++j) acc[i][j] = 0.0f;

  for (int ks = 0; ks < 16; ++ks) {
    const int cur = ks & 1;
    float4 bn0, bn1, an4;
    if (ks < 15) {
      const int k0 = (ks + 1) * 8;
      bn0 = *(const float4*)(W2 + (size_t)(k0 + bk0) * 9216 + C0 + bc0);
      bn1 = *(const float4*)(W2 + (size_t)(k0 + bk1) * 9216 + C0 + bc1);
      if (tid < 128)
        an4 = *(const float4*)(hiddenT + (size_t)(k0 + ak) * 1024 + g0 + an);
    }
    #pragma unroll
    for (int kk = 0; kk < 8; ++kk) {
      float4 a0 = *(const float4*)&ATs[cur][kk][r8];
      float4 a1 = *(const float4*)&ATs[cur][kk][r8 + 4];
      float4 b0 = *(const float4*)&Bs[cur][kk][c8];
      float4 b1 = *(const float4*)&Bs[cur][kk][c8 + 4];
      float av[8] = {a0.x, a0.y, a0.z, a0.w, a1.x, a1.y, a1.z, a1.w};
      float bv[8] = {b0.x, b0.y, b0.z, b0.w, b1.x, b1.y, b1.z, b1.w};
      #pragma unroll
      for (int i = 0; i < 8; ++i)
        #pragma unroll
        for (int j = 0; j < 8; ++j)
          acc[i][j] = fmaf(av[i], bv[j], acc[i][j]);
    }
    if (ks < 15) {
      const int nxt = cur ^ 1;
      *(float4*)&Bs[nxt][bk0][bc0] = bn0;
      *(float4*)&Bs[nxt][bk1][bc1] = bn1;
      if (tid < 128) *(float4*)&ATs[nxt][ak][an] = an4;
    }
    __syncthreads();
  }

  // ---- fused contraction into LDS ----
  const int j0 = C0 + c8;
  float4 bq0 = *(const float4*)(b2 + j0);
  float4 bq1 = *(const float4*)(b2 + j0 + 4);
  float bias[8] = {bq0.x, bq0.y, bq0.z, bq0.w, bq1.x, bq1.y, bq1.z, bq1.w};

  if (chunk < 16) {                       // w1: out_s[o] += xs[i]*tp
    const int i = j0 >> 6;
    const int o0 = j0 & 63;
    #pragma unroll
    for (int nn = 0; nn < 8; ++nn) {
      float xsv = hf[(size_t)(g0 + r8 + nn) * 160 + i];
      #pragma unroll
      for (int cc = 0; cc < 8; ++cc)
        atomicAdd(&valsS[r8 + nn][o0 + cc], xsv * (acc[nn][cc] + bias[cc]));
    }
  } else if (chunk < 24) {                // w2: sv[o] += xs[i]*tp
    const int t2 = j0 - 4096;
    const int i = t2 >> 5;
    const int o0 = t2 & 31;
    #pragma unroll
    for (int nn = 0; nn < 8; ++nn) {
      float xsv = hf[(size_t)(g0 + r8 + nn) * 160 + i];
      #pragma unroll
      for (int cc = 0; cc < 8; ++cc)
        atomicAdd(&svS[r8 + nn][o0 + cc], xsv * (acc[nn][cc] + bias[cc]));
    }
  } else if (chunk < 28) {                // w3: out_v[o][cc'] += xv[i][cc']*tp
    const int t2 = j0 - 6144;
    const int i = t2 >> 5;
    const int o0 = t2 & 31;
    #pragma unroll
    for (int nn = 0; nn < 8; ++nn) {
      const float* xvp = hf + (size_t)(g0 + r8 + nn) * 160 + 64 + 3 * i;
      float x0 = xvp[0], x1 = xvp[1], x2 = xvp[2];
      #pragma unroll
      for (int cc = 0; cc < 8; ++cc) {
        float tp = acc[nn][cc] + bias[cc];
        int base = 64 + 3 * (o0 + cc);
        atomicAdd(&valsS[r8 + nn][base + 0], x0 * tp);
        atomicAdd(&valsS[r8 + nn][base + 1], x1 * tp);
        atomicAdd(&valsS[r8 + nn][base + 2], x2 * tp);
      }
    }
  } else {                                // w4: out_s[o] += xvu[i]*tp
    const int t2 = j0 - 7168;
    const int i = t2 >> 6;
    const int o0 = t2 & 63;
    #pragma unroll
    for (int nn = 0; nn < 8; ++nn) {
      float xuv = xvu[(size_t)(g0 + r8 + nn) * 32 + i];
      #pragma unroll
      for (int cc = 0; cc < 8; ++cc)
        atomicAdd(&valsS[r8 + nn][o0 + cc], xuv * (acc[nn][cc] + bias[cc]));
    }
  }
  __syncthreads();

  // ---- flush to global (only the region this chunk-class touched) ----
  if (chunk < 16 || chunk >= 28) {        // scalar half
    for (int idx = tid; idx < 4096; idx += 256) {
      int n = idx >> 6, d = idx & 63;
      atomicAdd(&values[(size_t)(g0 + n) * 160 + d], ALPHAF * valsS[n][d]);
    }
  } else if (chunk < 24) {                // sv -> y1-weighted vector part
    for (int idx = tid; idx < 2048; idx += 256) {
      int n = idx >> 5, o = idx & 31;
      float s = ALPHAF * svS[n][o];
      float4 y = *(const float4*)(y1cw + (size_t)(g0 + n) * 4);
      size_t base = (size_t)(g0 + n) * 160 + 64 + 3 * o;
      atomicAdd(&values[base + 0], s * y.x);
      atomicAdd(&values[base + 1], s * y.y);
      atomicAdd(&values[base + 2], s * y.z);
    }
  } else {                                // w3 vector part
    for (int idx = tid; idx < 6144; idx += 256) {
      int n = idx / 96, d = idx - n * 96;
      atomicAdd(&values[(size_t)(g0 + n) * 160 + 64 + d], ALPHAF * valsS[n][64 + d]);
    }
  }
}

// ---------------------------------------------------------------------------
// K3 v3: gate MLP + aggregation, TWO energies per block. grid=1024, block=256.
// W1 stream from L2 amortized over 2 e's; one `values` read feeds both aggs.
// ---------------------------------------------------------------------------
__global__ void __launch_bounds__(256, 2) k_gate_agg(
    const float* __restrict__ Pa, const float* __restrict__ Pe,
    const float* __restrict__ Pn, const float* __restrict__ W1,
    const float* __restrict__ b1, const float* __restrict__ W2v,
    const float* __restrict__ b2s, const float* __restrict__ y1cw,
    const float* __restrict__ values, float* __restrict__ inv_agg) {
  const int bid = blockIdx.x;
  const int b = bid >> 6;
  const int e0 = (bid & 63) * 2, e1 = e0 + 1;
  const int tid = threadIdx.x;

  __shared__ float A0[64][129];
  __shared__ float A1[64][129];
  __shared__ float Prow0[128], Prow1[128];
  __shared__ float gpart0[64][17], gpart1[64][17];
  __shared__ float gateL0[64], gateL1[64];
  __shared__ float aggL0[160], aggL1[160];
  __shared__ float normS0, normS1;

  if (tid < 128) {
    float pa = Pa[b * 128 + tid];
    Prow0[tid] = pa + Pe[e0 * 128 + tid];
    Prow1[tid] = pa + Pe[e1 * 128 + tid];
  }
  __syncthreads();
  {
    const float* pn = Pn + (size_t)b * 64 * 128;
    for (int idx = tid; idx < 8192; idx += 256) {
      int k = idx & 127;
      float v = pn[idx];
      A0[idx >> 7][k] = silu_f(v + Prow0[k]);
      A1[idx >> 7][k] = silu_f(v + Prow1[k]);
    }
  }
  __syncthreads();

  const int rowg = tid >> 4, colg = tid & 15;
  const int r4 = rowg * 4, c8 = colg * 8;

  float acc0[4][8], acc1[4][8];
  #pragma unroll
  for (int i = 0; i < 4; ++i)
    #pragma unroll
    for (int jj = 0; jj < 8; ++jj) { acc0[i][jj] = 0.0f; acc1[i][jj] = 0.0f; }

  const float* wptr = W1 + c8;
  float4 w0c = *(const float4*)(wptr);
  float4 w1c = *(const float4*)(wptr + 4);
  #pragma unroll 2
  for (int k = 0; k < 128; ++k) {
    float4 w0n, w1n;
    if (k < 127) {
      w0n = *(const float4*)(wptr + (k + 1) * 128);
      w1n = *(const float4*)(wptr + (k + 1) * 128 + 4);
    }
    float wv[8] = {w0c.x, w0c.y, w0c.z, w0c.w, w1c.x, w1c.y, w1c.z, w1c.w};
    float a00 = A0[r4 + 0][k], a01 = A0[r4 + 1][k];
    float a02 = A0[r4 + 2][k], a03 = A0[r4 + 3][k];
    float a10 = A1[r4 + 0][k], a11 = A1[r4 + 1][k];
    float a12 = A1[r4 + 2][k], a13 = A1[r4 + 3][k];
    #pragma unroll
    for (int jj = 0; jj < 8; ++jj) {
      acc0[0][jj] = fmaf(a00, wv[jj], acc0[0][jj]);
      acc0[1][jj] = fmaf(a01, wv[jj], acc0[1][jj]);
      acc0[2][jj] = fmaf(a02, wv[jj], acc0[2][jj]);
      acc0[3][jj] = fmaf(a03, wv[jj], acc0[3][jj]);
      acc1[0][jj] = fmaf(a10, wv[jj], acc1[0][jj]);
      acc1[1][jj] = fmaf(a11, wv[jj], acc1[1][jj]);
      acc1[2][jj] = fmaf(a12, wv[jj], acc1[2][jj]);
      acc1[3][jj] = fmaf(a13, wv[jj], acc1[3][jj]);
    }
    w0c = w0n; w1c = w1n;
  }

  {
    float p0[4] = {0.f, 0.f, 0.f, 0.f};
    float p1[4] = {0.f, 0.f, 0.f, 0.f};
    #pragma unroll
    for (int jj = 0; jj < 8; ++jj) {
      float bb = b1[c8 + jj];
      float wg = W2v[c8 + jj];
      #pragma unroll
      for (int i = 0; i < 4; ++i) {
        p0[i] = fmaf(silu_f(acc0[i][jj] + bb), wg, p0[i]);
        p1[i] = fmaf(silu_f(acc1[i][jj] + bb), wg, p1[i]);
      }
    }
    #pragma unroll
    for (int i = 0; i < 4; ++i) {
      gpart0[r4 + i][colg] = p0[i];
      gpart1[r4 + i][colg] = p1[i];
    }
  }
  __syncthreads();

  if (tid < 128) {
    const int l = tid & 63;
    float s = 0.0f;
    if (tid < 64) {
      #pragma unroll
      for (int cg = 0; cg < 16; ++cg) s += gpart0[l][cg];
    } else {
      #pragma unroll
      for (int cg = 0; cg < 16; ++cg) s += gpart1[l][cg];
    }
    float gv = sigmoid_f(s + b2s[0]);
    gv *= y1cw[(b * 64 + l) * 4 + 3];
    if (tid < 64) gateL0[l] = gv; else gateL1[l] = gv;
    float t = gv;
    #pragma unroll
    for (int off = 32; off > 0; off >>= 1) t += __shfl_down(t, off);
    if (l == 0) {
      if (tid < 64) normS0 = fmaxf(t, 1e-8f);
      else normS1 = fmaxf(t, 1e-8f);
    }
  }
  __syncthreads();

  if (tid < 160) {
    float a0 = 0.0f, a1 = 0.0f;
    const float* vp = values + (size_t)b * 64 * 160 + tid;
    #pragma unroll 4
    for (int n = 0; n < 64; ++n) {
      float v = vp[n * 160];
      a0 = fmaf(gateL0[n], v, a0);
      a1 = fmaf(gateL1[n], v, a1);
    }
    aggL0[tid] = a0 / normS0;
    aggL1[tid] = a1 / normS1;
  }
  __syncthreads();
  if (tid < 192) {
    const int l = tid < 96 ? tid : tid - 96;
    const float* ag = tid < 96 ? aggL0 : aggL1;
    const int e = tid < 96 ? e0 : e1;
    float rv;
    if (l < 64) {
      rv = ag[l];
    } else {
      int o = l - 64;
      float a0 = ag[64 + o * 3 + 0];
      float a1 = ag[64 + o * 3 + 1];
      float a2 = ag[64 + o * 3 + 2];
      rv = sqrtf((a0 * a0 + a1 * a1 + a2 * a2) * (1.0f / 3.0f) + 1e-8f);
    }
    inv_agg[(size_t)(b * 128 + e) * 96 + l] = rv;
  }
}

// ---------------------------------------------------------------------------
// K4: MLP layer Y = act(X@W + b). 32-row tiles -> 64 blocks. K in {96,128}.
// ---------------------------------------------------------------------------
__global__ void __launch_bounds__(256) k_mlp(
    const float* __restrict__ X, const float* __restrict__ W,
    const float* __restrict__ bias, float* __restrict__ Y,
    int K, int act) {
  const int r0 = blockIdx.x * 32;
  const int tid = threadIdx.x;

  __shared__ float A[32][129];

  for (int idx = tid; idx < 32 * K; idx += 256) {
    int n = idx / K, k = idx - n * K;
    A[n][k] = X[(size_t)(r0 + n) * K + k];
  }
  __syncthreads();

  const int rowg = tid >> 4, colg = tid & 15;
  const int r2 = rowg * 2, c8 = colg * 8;

  float acc[2][8];
  #pragma unroll
  for (int i = 0; i < 2; ++i)
    #pragma unroll
    for (int jj = 0; jj < 8; ++jj) acc[i][jj] = 0.0f;

  const float* wptr = W + c8;
  #pragma unroll 4
  for (int k = 0; k < K; ++k) {
    float4 w0 = *(const float4*)(wptr + k * 128);
    float4 w1v = *(const float4*)(wptr + k * 128 + 4);
    float av0 = A[r2 + 0][k];
    float av1 = A[r2 + 1][k];
    float wv[8] = {w0.x, w0.y, w0.z, w0.w, w1v.x, w1v.y, w1v.z, w1v.w};
    #pragma unroll
    for (int jj = 0; jj < 8; ++jj) {
      acc[0][jj] = fmaf(av0, wv[jj], acc[0][jj]);
      acc[1][jj] = fmaf(av1, wv[jj], acc[1][jj]);
    }
  }

  #pragma unroll
  for (int jj = 0; jj < 8; ++jj) {
    float bb = bias[c8 + jj];
    #pragma unroll
    for (int i = 0; i < 2; ++i) {
      float v = acc[i][jj] + bb;
      if (act) v = silu_f(v);
      Y[(size_t)(r0 + r2 + i) * 128 + c8 + jj] = v;
    }
  }
}

// ---------------------------------------------------------------------------
extern "C" void kernel_launch(void* const* d_in, const int* in_sizes, int n_in,
                              void* d_out, int out_size, void* d_ws, size_t ws_size,
                              hipStream_t stream) {
  const float* hf    = (const float*)d_in[0];
  const int*   z     = (const int*)  d_in[1];
  const float* pos   = (const float*)d_in[2];
  const float* e_feat= (const float*)d_in[4];
  const float* z_emb = (const float*)d_in[5];
  const float* vwW0  = (const float*)d_in[6];
  const float* vwb0  = (const float*)d_in[7];
  const float* vwW1  = (const float*)d_in[8];
  const float* vwb1  = (const float*)d_in[9];
  const float* vwW2  = (const float*)d_in[10];
  const float* vwb2  = (const float*)d_in[11];
  const float* scW0  = (const float*)d_in[12];
  const float* scb0  = (const float*)d_in[13];
  const float* scW1  = (const float*)d_in[14];
  const float* scb1  = (const float*)d_in[15];
  const float* scW2  = (const float*)d_in[16];
  const float* scb2  = (const float*)d_in[17];
  const float* oW0   = (const float*)d_in[18];
  const float* ob0   = (const float*)d_in[19];
  const float* oW1   = (const float*)d_in[20];
  const float* ob1   = (const float*)d_in[21];
  const float* oW2   = (const float*)d_in[22];
  const float* ob2   = (const float*)d_in[23];
  float* out = (float*)d_out;

  float* ws = (float*)d_ws;
  float* hiddenT = ws;                // 128*1024 (k-major, transposed)
  float* Pn     = hiddenT + 131072;   // 1024*128
  float* Pa     = Pn + 131072;        // 16*128
  float* Pe     = Pa + 2048;          // 128*128
  float* xvu    = Pe + 16384;         // 1024*32
  float* y1cw   = xvu + 32768;        // 1024*4
  float* values = y1cw + 4096;        // 1024*160
  float* invagg = values + 163840;    // 2048*96
  float* H1     = invagg + 196608;    // 2048*128
  float* H2     = H1 + 262144;        // 2048*128

  hipMemsetAsync(values, 0, 163840 * sizeof(float), stream);

  k_prep<<<256, 128, 0, stream>>>(hf, z, pos, z_emb, vwW0, vwb0, vwW1, vwb1,
                                  scW0, hiddenT, Pn, Pa, xvu, y1cw);
  k_pe<<<128, 128, 0, stream>>>(e_feat, scW0, scb0, Pe);
  k_tp<<<dim3(16, 36), 256, 0, stream>>>(hiddenT, vwW2, vwb2, hf, xvu, y1cw, values);
  k_gate_agg<<<1024, 256, 0, stream>>>(Pa, Pe, Pn, scW1, scb1, scW2, scb2,
                                       y1cw, values, invagg);
  k_mlp<<<64, 256, 0, stream>>>(invagg, oW0, ob0, H1, 96, 1);
  k_mlp<<<64, 256, 0, stream>>>(H1, oW1, ob1, H2, 128, 1);
  k_mlp<<<64, 256, 0, stream>>>(H2, oW2, ob2, out, 128, 0);
}

// Round 6
// 416.478 us; speedup vs baseline: 1.3417x; 1.1605x over previous
//
#include <hip/hip_runtime.h>
#include <hip/hip_bf16.h>
#include <math.h>

// Sizes: B=16, N=64, nE=128, H=128, LAT=128, NS=64, NV=32, INV=96, D_NODE=160
#define SQRT3F 1.7320508075688772f
#define ALPHAF 0.10206207261596577f  // 1/sqrt(96)
#define PIF 3.14159265358979323846f

typedef short v8s __attribute__((ext_vector_type(8)));
typedef float v4f __attribute__((ext_vector_type(4)));

__device__ __forceinline__ float silu_f(float x) {
  return x / (1.0f + __expf(-x));
}
__device__ __forceinline__ float sigmoid_f(float x) {
  return 1.0f / (1.0f + __expf(-x));
}
__device__ __forceinline__ unsigned short f2bf(float f) {
  unsigned int u = __float_as_uint(f);
  unsigned int r = (u + 0x7fffu + ((u >> 16) & 1u)) >> 16;
  return (unsigned short)r;
}
__device__ __forceinline__ float bf2f(unsigned short h) {
  return __uint_as_float(((unsigned int)h) << 16);
}

// ---------------------------------------------------------------------------
// K-1: cast+transpose W2 (128 x 9216 fp32) -> W2Th/W2Tl (9216 x 128 bf16,
// hi/lo split). grid=144 (64-col tiles), block=256.
// ---------------------------------------------------------------------------
__global__ void __launch_bounds__(256) k_castw2(
    const float* __restrict__ W2, unsigned short* __restrict__ W2Th,
    unsigned short* __restrict__ W2Tl) {
  const int C0 = blockIdx.x * 64;
  const int tid = threadIdx.x;
  __shared__ float T[64][129];

  for (int idx = tid; idx < 128 * 64; idx += 256) {
    int k = idx >> 6, c = idx & 63;
    T[c][k] = W2[(size_t)k * 9216 + C0 + c];
  }
  __syncthreads();
  // write 8 k's per thread per iter
  for (int idx = tid; idx < 64 * 16; idx += 256) {
    int c = idx >> 4, k8 = (idx & 15) * 8;
    unsigned short hv[8], lv[8];
    #pragma unroll
    for (int j = 0; j < 8; ++j) {
      float w = T[c][k8 + j];
      unsigned short h = f2bf(w);
      hv[j] = h;
      lv[j] = f2bf(w - bf2f(h));
    }
    size_t base = (size_t)(C0 + c) * 128 + k8;
    *(uint4*)&W2Th[base] = *(uint4*)hv;
    *(uint4*)&W2Tl[base] = *(uint4*)lv;
  }
}

// ---------------------------------------------------------------------------
// K0: per-node prep, 4 nodes per block. grid=256, block=128.
// Emits hidden as bf16 hi/lo, node-major [1024][128].
// ---------------------------------------------------------------------------
__global__ void k_prep(const float* __restrict__ hf, const int* __restrict__ z,
                       const float* __restrict__ pos, const float* __restrict__ z_emb,
                       const float* __restrict__ vwW0, const float* __restrict__ vwb0,
                       const float* __restrict__ vwW1, const float* __restrict__ vwb1,
                       const float* __restrict__ scW0,
                       unsigned short* __restrict__ hTh, unsigned short* __restrict__ hTl,
                       float* __restrict__ Pn, float* __restrict__ Pa,
                       float* __restrict__ xvu, float* __restrict__ y1cw) {
  const int g0 = blockIdx.x * 4;
  const int b = g0 >> 6;
  const int t = threadIdx.x;

  __shared__ float vin[4][64];
  __shared__ float invn[4][96];
  __shared__ float h0[4][128];
  __shared__ float uS[4][3];
  __shared__ float rS[4];

  if (t < 4) {
    const int g = g0 + t;
    float px = pos[g * 3 + 0] - pos[(b * 64) * 3 + 0];
    float py = pos[g * 3 + 1] - pos[(b * 64) * 3 + 1];
    float pz = pos[g * 3 + 2] - pos[(b * 64) * 3 + 2];
    float r = sqrtf(px * px + py * py + pz * pz + 1e-12f);
    float rm = fmaxf(r, 1e-8f);
    uS[t][0] = px / rm; uS[t][1] = py / rm; uS[t][2] = pz / rm;
    rS[t] = r;
  }
  __syncthreads();

  if (t < 32) {
    const float delta = 6.0f / 31.0f;
    const float gamma = 1.0f / (delta * delta + 1e-12f);
    #pragma unroll
    for (int nn = 0; nn < 4; ++nn) {
      int zi = z[g0 + nn];
      vin[nn][t] = z_emb[zi * 32 + t];
      float rc = fminf(rS[nn], 6.0f);
      float d = rc - (float)t * delta;
      vin[nn][32 + t] = __expf(-gamma * d * d);
      float a = hf[(g0 + nn) * 160 + 64 + t * 3 + 0] * uS[nn][0]
              + hf[(g0 + nn) * 160 + 64 + t * 3 + 1] * uS[nn][1]
              + hf[(g0 + nn) * 160 + 64 + t * 3 + 2] * uS[nn][2];
      xvu[(g0 + nn) * 32 + t] = a;
    }
  }
  if (t < 96) {
    #pragma unroll
    for (int nn = 0; nn < 4; ++nn) {
      const int g = g0 + nn;
      if (t < 64) {
        invn[nn][t] = hf[g * 160 + t];
      } else {
        int o = t - 64;
        float v0 = hf[g * 160 + 64 + o * 3 + 0];
        float v1 = hf[g * 160 + 64 + o * 3 + 1];
        float v2 = hf[g * 160 + 64 + o * 3 + 2];
        invn[nn][t] = sqrtf((v0 * v0 + v1 * v1 + v2 * v2) * (1.0f / 3.0f) + 1e-8f);
      }
    }
  }
  if (t < 4) {
    const int n = (g0 + t) & 63;
    float r = rS[t];
    float cw = 0.0f;
    if (r <= 6.0f && n != 0) cw = 0.5f * (cosf(PIF * r * (1.0f / 6.0f)) + 1.0f);
    y1cw[(g0 + t) * 4 + 0] = SQRT3F * uS[t][0];
    y1cw[(g0 + t) * 4 + 1] = SQRT3F * uS[t][1];
    y1cw[(g0 + t) * 4 + 2] = SQRT3F * uS[t][2];
    y1cw[(g0 + t) * 4 + 3] = cw;
  }
  __syncthreads();

  {
    float a0 = vwb0[t], a1 = a0, a2 = a0, a3 = a0;
    #pragma unroll 8
    for (int k = 0; k < 64; ++k) {
      float w = vwW0[k * 128 + t];
      a0 = fmaf(vin[0][k], w, a0);
      a1 = fmaf(vin[1][k], w, a1);
      a2 = fmaf(vin[2][k], w, a2);
      a3 = fmaf(vin[3][k], w, a3);
    }
    h0[0][t] = silu_f(a0); h0[1][t] = silu_f(a1);
    h0[2][t] = silu_f(a2); h0[3][t] = silu_f(a3);
  }
  __syncthreads();
  {
    float a0 = vwb1[t], a1 = a0, a2 = a0, a3 = a0;
    #pragma unroll 8
    for (int k = 0; k < 128; ++k) {
      float w = vwW1[k * 128 + t];
      a0 = fmaf(h0[0][k], w, a0);
      a1 = fmaf(h0[1][k], w, a1);
      a2 = fmaf(h0[2][k], w, a2);
      a3 = fmaf(h0[3][k], w, a3);
    }
    float hv[4] = {silu_f(a0), silu_f(a1), silu_f(a2), silu_f(a3)};
    #pragma unroll
    for (int nn = 0; nn < 4; ++nn) {
      unsigned short hh = f2bf(hv[nn]);
      hTh[(size_t)(g0 + nn) * 128 + t] = hh;
      hTl[(size_t)(g0 + nn) * 128 + t] = f2bf(hv[nn] - bf2f(hh));
    }
  }
  {
    float p0 = 0.f, p1 = 0.f, p2 = 0.f, p3 = 0.f;
    #pragma unroll 8
    for (int k = 0; k < 96; ++k) {
      float w = scW0[(96 + k) * 128 + t];
      p0 = fmaf(invn[0][k], w, p0);
      p1 = fmaf(invn[1][k], w, p1);
      p2 = fmaf(invn[2][k], w, p2);
      p3 = fmaf(invn[3][k], w, p3);
    }
    #pragma unroll 8
    for (int k = 0; k < 64; ++k) {
      float w = scW0[(192 + k) * 128 + t];
      p0 = fmaf(vin[0][k], w, p0);
      p1 = fmaf(vin[1][k], w, p1);
      p2 = fmaf(vin[2][k], w, p2);
      p3 = fmaf(vin[3][k], w, p3);
    }
    Pn[(g0 + 0) * 128 + t] = p0;
    Pn[(g0 + 1) * 128 + t] = p1;
    Pn[(g0 + 2) * 128 + t] = p2;
    Pn[(g0 + 3) * 128 + t] = p3;
  }
  if ((g0 & 63) == 0) {
    float p = 0.0f;
    #pragma unroll 8
    for (int k = 0; k < 96; ++k) p = fmaf(invn[0][k], scW0[k * 128 + t], p);
    Pa[b * 128 + t] = p;
  }
}

// ---------------------------------------------------------------------------
// KPe: Pe[e][t] = sc_b0[t] + e_feat[e]@We. grid=128, block=128.
// ---------------------------------------------------------------------------
__global__ void k_pe(const float* __restrict__ e_feat, const float* __restrict__ scW0,
                     const float* __restrict__ scb0, float* __restrict__ Pe) {
  const int e = blockIdx.x;
  const int t = threadIdx.x;
  float a = scb0[t];
  #pragma unroll
  for (int k = 0; k < 16; ++k) a = fmaf(e_feat[e * 16 + k], scW0[(256 + k) * 128 + t], a);
  Pe[e * 128 + t] = a;
}

// ---------------------------------------------------------------------------
// K2 v6: MFMA bf16 (3-term hi/lo split) GEMM + fused contraction.
// grid = (16 node-tiles of 64, 36 col-chunks of 256), block = 256 (4 waves).
// Fragment maps (verified m89/m91): A[m=lane&15][k=q*8+j], B[n=lane&15][k],
// D row=q*4+reg, col=lane&15.
// ---------------------------------------------------------------------------
union SMemU {
  struct {
    unsigned short Ah[64][40];
    unsigned short Al[64][40];
    unsigned short Bh[256][40];
    unsigned short Bl[256][40];
  } mm;                                   // 51200 B
  struct {
    float vals[64][160];
    float sv[64][32];
  } ep;                                   // 49152 B
};

__global__ void __launch_bounds__(256, 3) k_tp(
    const unsigned short* __restrict__ hTh, const unsigned short* __restrict__ hTl,
    const unsigned short* __restrict__ W2Th, const unsigned short* __restrict__ W2Tl,
    const float* __restrict__ b2, const float* __restrict__ hf,
    const float* __restrict__ xvu, const float* __restrict__ y1cw,
    float* __restrict__ values) {
  const int g0 = blockIdx.x * 64;
  const int chunk = blockIdx.y;
  const int C0 = chunk * 256;
  const int tid = threadIdx.x;

  __shared__ SMemU sm;

  const int w = tid >> 6;        // wave 0..3
  const int l = tid & 63;
  const int q = l >> 4;          // quad
  const int cq = l & 15;

  // staging slots
  const int snode = tid >> 2;            // 0..63
  const int sko = (tid & 3) * 8;         // 0,8,16,24

  v4f acc[16];
  #pragma unroll
  for (int t = 0; t < 16; ++t) acc[t] = (v4f){0.f, 0.f, 0.f, 0.f};

  for (int ks = 0; ks < 4; ++ks) {
    const int kbase = ks * 32;
    // global -> regs
    uint4 ahv = *(const uint4*)&hTh[(size_t)(g0 + snode) * 128 + kbase + sko];
    uint4 alv = *(const uint4*)&hTl[(size_t)(g0 + snode) * 128 + kbase + sko];
    uint4 bhv[4], blv[4];
    #pragma unroll
    for (int rep = 0; rep < 4; ++rep) {
      const int col = snode + 64 * rep;
      bhv[rep] = *(const uint4*)&W2Th[(size_t)(C0 + col) * 128 + kbase + sko];
      blv[rep] = *(const uint4*)&W2Tl[(size_t)(C0 + col) * 128 + kbase + sko];
    }
    __syncthreads();   // previous compute done
    *(uint4*)&sm.mm.Ah[snode][sko] = ahv;
    *(uint4*)&sm.mm.Al[snode][sko] = alv;
    #pragma unroll
    for (int rep = 0; rep < 4; ++rep) {
      const int col = snode + 64 * rep;
      *(uint4*)&sm.mm.Bh[col][sko] = bhv[rep];
      *(uint4*)&sm.mm.Bl[col][sko] = blv[rep];
    }
    __syncthreads();

    const int m = w * 16 + cq;
    v8s ah = *(const v8s*)&sm.mm.Ah[m][q * 8];
    v8s al = *(const v8s*)&sm.mm.Al[m][q * 8];
    #pragma unroll
    for (int t = 0; t < 16; ++t) {
      v8s bh = *(const v8s*)&sm.mm.Bh[t * 16 + cq][q * 8];
      v8s bl = *(const v8s*)&sm.mm.Bl[t * 16 + cq][q * 8];
      acc[t] = __builtin_amdgcn_mfma_f32_16x16x32_bf16(ah, bh, acc[t], 0, 0, 0);
      acc[t] = __builtin_amdgcn_mfma_f32_16x16x32_bf16(al, bh, acc[t], 0, 0, 0);
      acc[t] = __builtin_amdgcn_mfma_f32_16x16x32_bf16(ah, bl, acc[t], 0, 0, 0);
    }
  }
  __syncthreads();   // all MFMA reads done; LDS reused for epilogue

  // zero epilogue accumulators
  for (int idx = tid; idx < 64 * 160; idx += 256) ((float*)sm.ep.vals)[idx] = 0.0f;
  for (int idx = tid; idx < 64 * 32; idx += 256) ((float*)sm.ep.sv)[idx] = 0.0f;
  __syncthreads();

  // lane holds, for tile t: D rows q*4+r (node = w*16+q*4+r), col C0+t*16+cq
  const int w16q4 = w * 16 + q * 4;

  if (chunk < 16) {                       // w1: out_s[o] += xs[i]*tp
    #pragma unroll
    for (int r = 0; r < 4; ++r) {
      const int n = w16q4 + r;
      const float* hfrow = hf + (size_t)(g0 + n) * 160;
      #pragma unroll
      for (int tl = 0; tl < 4; ++tl) {
        float s = 0.f;
        #pragma unroll
        for (int th = 0; th < 4; ++th) {
          const int t = tl + 4 * th;
          float tp = acc[t][r] + b2[C0 + t * 16 + cq];
          s = fmaf(hfrow[chunk * 4 + th], tp, s);
        }
        atomicAdd(&sm.ep.vals[n][tl * 16 + cq], s);
      }
    }
  } else if (chunk < 24) {                // w2: sv[o] += xs[i]*tp
    #pragma unroll
    for (int r = 0; r < 4; ++r) {
      const int n = w16q4 + r;
      const float* hfrow = hf + (size_t)(g0 + n) * 160;
      #pragma unroll
      for (int tl = 0; tl < 2; ++tl) {
        float s = 0.f;
        #pragma unroll
        for (int th = 0; th < 8; ++th) {
          const int t = tl + 2 * th;
          float tp = acc[t][r] + b2[C0 + t * 16 + cq];
          s = fmaf(hfrow[(chunk - 16) * 8 + th], tp, s);
        }
        atomicAdd(&sm.ep.sv[n][tl * 16 + cq], s);
      }
    }
  } else if (chunk < 28) {                // w3: out_v[o][c'] += xv[i][c']*tp
    #pragma unroll
    for (int r = 0; r < 4; ++r) {
      const int n = w16q4 + r;
      const float* hfrow = hf + (size_t)(g0 + n) * 160;
      #pragma unroll
      for (int tl = 0; tl < 2; ++tl) {
        float s0 = 0.f, s1 = 0.f, s2 = 0.f;
        #pragma unroll
        for (int th = 0; th < 8; ++th) {
          const int t = tl + 2 * th;
          const int i = (chunk - 24) * 8 + th;
          float tp = acc[t][r] + b2[C0 + t * 16 + cq];
          s0 = fmaf(hfrow[64 + 3 * i + 0], tp, s0);
          s1 = fmaf(hfrow[64 + 3 * i + 1], tp, s1);
          s2 = fmaf(hfrow[64 + 3 * i + 2], tp, s2);
        }
        const int base = 64 + 3 * (tl * 16 + cq);
        atomicAdd(&sm.ep.vals[n][base + 0], s0);
        atomicAdd(&sm.ep.vals[n][base + 1], s1);
        atomicAdd(&sm.ep.vals[n][base + 2], s2);
      }
    }
  } else {                                // w4: out_s[o] += xvu[i]*tp
    #pragma unroll
    for (int r = 0; r < 4; ++r) {
      const int n = w16q4 + r;
      const float* xurow = xvu + (size_t)(g0 + n) * 32;
      #pragma unroll
      for (int tl = 0; tl < 4; ++tl) {
        float s = 0.f;
        #pragma unroll
        for (int th = 0; th < 4; ++th) {
          const int t = tl + 4 * th;
          float tp = acc[t][r] + b2[C0 + t * 16 + cq];
          s = fmaf(xurow[(chunk - 28) * 4 + th], tp, s);
        }
        atomicAdd(&sm.ep.vals[n][tl * 16 + cq], s);
      }
    }
  }
  __syncthreads();

  // flush to global (only region this chunk-class touched)
  if (chunk < 16 || chunk >= 28) {        // scalar half
    for (int idx = tid; idx < 4096; idx += 256) {
      int n = idx >> 6, d = idx & 63;
      atomicAdd(&values[(size_t)(g0 + n) * 160 + d], ALPHAF * sm.ep.vals[n][d]);
    }
  } else if (chunk < 24) {                // sv -> y1-weighted vector part
    for (int idx = tid; idx < 2048; idx += 256) {
      int n = idx >> 5, o = idx & 31;
      float s = ALPHAF * sm.ep.sv[n][o];
      float4 y = *(const float4*)(y1cw + (size_t)(g0 + n) * 4);
      size_t base = (size_t)(g0 + n) * 160 + 64 + 3 * o;
      atomicAdd(&values[base + 0], s * y.x);
      atomicAdd(&values[base + 1], s * y.y);
      atomicAdd(&values[base + 2], s * y.z);
    }
  } else {                                // w3 vector part
    for (int idx = tid; idx < 6144; idx += 256) {
      int n = idx / 96, d = idx - n * 96;
      atomicAdd(&values[(size_t)(g0 + n) * 160 + 64 + d], ALPHAF * sm.ep.vals[n][64 + d]);
    }
  }
}

// ---------------------------------------------------------------------------
// K3: gate MLP + aggregation per (b,e). grid=2048, block=256. (R3 version)
// ---------------------------------------------------------------------------
__global__ void __launch_bounds__(256) k_gate_agg(
    const float* __restrict__ Pa, const float* __restrict__ Pe,
    const float* __restrict__ Pn, const float* __restrict__ W1,
    const float* __restrict__ b1, const float* __restrict__ W2v,
    const float* __restrict__ b2s, const float* __restrict__ y1cw,
    const float* __restrict__ values, float* __restrict__ inv_agg) {
  const int bid = blockIdx.x;
  const int b = bid >> 7, e = bid & 127;
  const int tid = threadIdx.x;

  __shared__ float A[64][129];
  __shared__ float Prow[128];
  __shared__ float gpart[64][17];
  __shared__ float gateL[64];
  __shared__ float aggL[160];
  __shared__ float normS;

  if (tid < 128) Prow[tid] = Pa[b * 128 + tid] + Pe[e * 128 + tid];
  __syncthreads();
  {
    const float* pn = Pn + (size_t)b * 64 * 128;
    for (int idx = tid; idx < 8192; idx += 256) {
      int n = idx >> 7, k = idx & 127;
      A[n][k] = silu_f(pn[idx] + Prow[k]);
    }
  }
  __syncthreads();

  const int rowg = tid >> 4, colg = tid & 15;
  const int r4 = rowg * 4, c8 = colg * 8;

  float acc[4][8];
  #pragma unroll
  for (int i = 0; i < 4; ++i)
    #pragma unroll
    for (int jj = 0; jj < 8; ++jj) acc[i][jj] = 0.0f;

  const float* wptr = W1 + c8;
  float4 w0c = *(const float4*)(wptr);
  float4 w1c = *(const float4*)(wptr + 4);
  #pragma unroll 2
  for (int k = 0; k < 128; ++k) {
    float4 w0n, w1n;
    if (k < 127) {
      w0n = *(const float4*)(wptr + (k + 1) * 128);
      w1n = *(const float4*)(wptr + (k + 1) * 128 + 4);
    }
    float av0 = A[r4 + 0][k];
    float av1 = A[r4 + 1][k];
    float av2 = A[r4 + 2][k];
    float av3 = A[r4 + 3][k];
    float wv[8] = {w0c.x, w0c.y, w0c.z, w0c.w, w1c.x, w1c.y, w1c.z, w1c.w};
    #pragma unroll
    for (int jj = 0; jj < 8; ++jj) {
      acc[0][jj] = fmaf(av0, wv[jj], acc[0][jj]);
      acc[1][jj] = fmaf(av1, wv[jj], acc[1][jj]);
      acc[2][jj] = fmaf(av2, wv[jj], acc[2][jj]);
      acc[3][jj] = fmaf(av3, wv[jj], acc[3][jj]);
    }
    w0c = w0n; w1c = w1n;
  }

  float p[4] = {0.0f, 0.0f, 0.0f, 0.0f};
  #pragma unroll
  for (int jj = 0; jj < 8; ++jj) {
    float bb = b1[c8 + jj];
    float wg = W2v[c8 + jj];
    #pragma unroll
    for (int i = 0; i < 4; ++i) {
      float h = silu_f(acc[i][jj] + bb);
      p[i] = fmaf(h, wg, p[i]);
    }
  }
  #pragma unroll
  for (int i = 0; i < 4; ++i) gpart[r4 + i][colg] = p[i];
  __syncthreads();

  if (tid < 64) {
    float s = 0.0f;
    #pragma unroll
    for (int cg = 0; cg < 16; ++cg) s += gpart[tid][cg];
    float gv = sigmoid_f(s + b2s[0]);
    gv *= y1cw[(b * 64 + tid) * 4 + 3];
    gateL[tid] = gv;
    float t = gv;
    #pragma unroll
    for (int off = 32; off > 0; off >>= 1) t += __shfl_down(t, off);
    if (tid == 0) normS = fmaxf(t, 1e-8f);
  }
  __syncthreads();

  if (tid < 160) {
    float a = 0.0f;
    const float* vp = values + (size_t)b * 64 * 160 + tid;
    #pragma unroll 4
    for (int n = 0; n < 64; ++n) a = fmaf(gateL[n], vp[n * 160], a);
    aggL[tid] = a / normS;
  }
  __syncthreads();
  if (tid < 96) {
    float rv;
    if (tid < 64) {
      rv = aggL[tid];
    } else {
      int o = tid - 64;
      float a0 = aggL[64 + o * 3 + 0];
      float a1 = aggL[64 + o * 3 + 1];
      float a2 = aggL[64 + o * 3 + 2];
      rv = sqrtf((a0 * a0 + a1 * a1 + a2 * a2) * (1.0f / 3.0f) + 1e-8f);
    }
    inv_agg[bid * 96 + tid] = rv;
  }
}

// ---------------------------------------------------------------------------
// K4: MLP layer Y = act(X@W + b). 32-row tiles -> 64 blocks. K in {96,128}.
// ---------------------------------------------------------------------------
__global__ void __launch_bounds__(256) k_mlp(
    const float* __restrict__ X, const float* __restrict__ W,
    const float* __restrict__ bias, float* __restrict__ Y,
    int K, int act) {
  const int r0 = blockIdx.x * 32;
  const int tid = threadIdx.x;

  __shared__ float A[32][129];

  for (int idx = tid; idx < 32 * K; idx += 256) {
    int n = idx / K, k = idx - n * K;
    A[n][k] = X[(size_t)(r0 + n) * K + k];
  }
  __syncthreads();

  const int rowg = tid >> 4, colg = tid & 15;
  const int r2 = rowg * 2, c8 = colg * 8;

  float acc[2][8];
  #pragma unroll
  for (int i = 0; i < 2; ++i)
    #pragma unroll
    for (int jj = 0; jj < 8; ++jj) acc[i][jj] = 0.0f;

  const float* wptr = W + c8;
  #pragma unroll 4
  for (int k = 0; k < K; ++k) {
    float4 w0 = *(const float4*)(wptr + k * 128);
    float4 w1v = *(const float4*)(wptr + k * 128 + 4);
    float av0 = A[r2 + 0][k];
    float av1 = A[r2 + 1][k];
    float wv[8] = {w0.x, w0.y, w0.z, w0.w, w1v.x, w1v.y, w1v.z, w1v.w};
    #pragma unroll
    for (int jj = 0; jj < 8; ++jj) {
      acc[0][jj] = fmaf(av0, wv[jj], acc[0][jj]);
      acc[1][jj] = fmaf(av1, wv[jj], acc[1][jj]);
    }
  }

  #pragma unroll
  for (int jj = 0; jj < 8; ++jj) {
    float bb = bias[c8 + jj];
    #pragma unroll
    for (int i = 0; i < 2; ++i) {
      float v = acc[i][jj] + bb;
      if (act) v = silu_f(v);
      Y[(size_t)(r0 + r2 + i) * 128 + c8 + jj] = v;
    }
  }
}

// ---------------------------------------------------------------------------
extern "C" void kernel_launch(void* const* d_in, const int* in_sizes, int n_in,
                              void* d_out, int out_size, void* d_ws, size_t ws_size,
                              hipStream_t stream) {
  const float* hf    = (const float*)d_in[0];
  const int*   z     = (const int*)  d_in[1];
  const float* pos   = (const float*)d_in[2];
  const float* e_feat= (const float*)d_in[4];
  const float* z_emb = (const float*)d_in[5];
  const float* vwW0  = (const float*)d_in[6];
  const float* vwb0  = (const float*)d_in[7];
  const float* vwW1  = (const float*)d_in[8];
  const float* vwb1  = (const float*)d_in[9];
  const float* vwW2  = (const float*)d_in[10];
  const float* vwb2  = (const float*)d_in[11];
  const float* scW0  = (const float*)d_in[12];
  const float* scb0  = (const float*)d_in[13];
  const float* scW1  = (const float*)d_in[14];
  const float* scb1  = (const float*)d_in[15];
  const float* scW2  = (const float*)d_in[16];
  const float* scb2  = (const float*)d_in[17];
  const float* oW0   = (const float*)d_in[18];
  const float* ob0   = (const float*)d_in[19];
  const float* oW1   = (const float*)d_in[20];
  const float* ob1   = (const float*)d_in[21];
  const float* oW2   = (const float*)d_in[22];
  const float* ob2   = (const float*)d_in[23];
  float* out = (float*)d_out;

  float* ws = (float*)d_ws;
  // bf16 buffers (sized in float units)
  unsigned short* W2Th = (unsigned short*)(ws);            // 1179648 u16 = 589824 fl
  unsigned short* W2Tl = (unsigned short*)(ws + 589824);   // 589824 fl
  unsigned short* hTh  = (unsigned short*)(ws + 1179648);  // 65536 fl
  unsigned short* hTl  = (unsigned short*)(ws + 1245184);  // 65536 fl
  float* Pn     = ws + 1310720;   // 131072
  float* Pa     = Pn + 131072;    // 2048
  float* Pe     = Pa + 2048;      // 16384
  float* xvu    = Pe + 16384;     // 32768
  float* y1cw   = xvu + 32768;    // 4096
  float* values = y1cw + 4096;    // 163840
  float* invagg = values + 163840;// 196608
  // H1/H2 alias the W2T region (dead after k_tp)
  float* H1     = ws;             // 262144
  float* H2     = ws + 262144;    // 262144

  hipMemsetAsync(values, 0, 163840 * sizeof(float), stream);

  k_castw2<<<144, 256, 0, stream>>>(vwW2, W2Th, W2Tl);
  k_prep<<<256, 128, 0, stream>>>(hf, z, pos, z_emb, vwW0, vwb0, vwW1, vwb1,
                                  scW0, hTh, hTl, Pn, Pa, xvu, y1cw);
  k_pe<<<128, 128, 0, stream>>>(e_feat, scW0, scb0, Pe);
  k_tp<<<dim3(16, 36), 256, 0, stream>>>(hTh, hTl, W2Th, W2Tl, vwb2, hf, xvu,
                                         y1cw, values);
  k_gate_agg<<<2048, 256, 0, stream>>>(Pa, Pe, Pn, scW1, scb1, scW2, scb2,
                                       y1cw, values, invagg);
  k_mlp<<<64, 256, 0, stream>>>(invagg, oW0, ob0, H1, 96, 1);
  k_mlp<<<64, 256, 0, stream>>>(H1, oW1, ob1, H2, 128, 1);
  k_mlp<<<64, 256, 0, stream>>>(H2, oW2, ob2, out, 128, 0);
}

// Round 7
// 346.519 us; speedup vs baseline: 1.6125x; 1.2019x over previous
//
#include <hip/hip_runtime.h>
#include <hip/hip_bf16.h>
#include <math.h>

// Sizes: B=16, N=64, nE=128, H=128, LAT=128, NS=64, NV=32, INV=96, D_NODE=160
#define SQRT3F 1.7320508075688772f
#define ALPHAF 0.10206207261596577f  // 1/sqrt(96)
#define PIF 3.14159265358979323846f

typedef short v8s __attribute__((ext_vector_type(8)));
typedef float v4f __attribute__((ext_vector_type(4)));

__device__ __forceinline__ float silu_f(float x) {
  return x / (1.0f + __expf(-x));
}
__device__ __forceinline__ float sigmoid_f(float x) {
  return 1.0f / (1.0f + __expf(-x));
}
__device__ __forceinline__ unsigned short f2bf(float f) {
  unsigned int u = __float_as_uint(f);
  unsigned int r = (u + 0x7fffu + ((u >> 16) & 1u)) >> 16;
  return (unsigned short)r;
}
__device__ __forceinline__ float bf2f(unsigned short h) {
  return __uint_as_float(((unsigned int)h) << 16);
}

// ---------------------------------------------------------------------------
// K-1: cast+transpose W2 (128 x 9216 fp32) -> W2Th/W2Tl (9216 x 128 bf16,
// hi/lo split). grid=144 (64-col tiles), block=256.
// ---------------------------------------------------------------------------
__global__ void __launch_bounds__(256) k_castw2(
    const float* __restrict__ W2, unsigned short* __restrict__ W2Th,
    unsigned short* __restrict__ W2Tl) {
  const int C0 = blockIdx.x * 64;
  const int tid = threadIdx.x;
  __shared__ float T[64][129];

  for (int idx = tid; idx < 128 * 64; idx += 256) {
    int k = idx >> 6, c = idx & 63;
    T[c][k] = W2[(size_t)k * 9216 + C0 + c];
  }
  __syncthreads();
  for (int idx = tid; idx < 64 * 16; idx += 256) {
    int c = idx >> 4, k8 = (idx & 15) * 8;
    unsigned short hv[8], lv[8];
    #pragma unroll
    for (int j = 0; j < 8; ++j) {
      float w = T[c][k8 + j];
      unsigned short h = f2bf(w);
      hv[j] = h;
      lv[j] = f2bf(w - bf2f(h));
    }
    size_t base = (size_t)(C0 + c) * 128 + k8;
    *(uint4*)&W2Th[base] = *(uint4*)hv;
    *(uint4*)&W2Tl[base] = *(uint4*)lv;
  }
}

// ---------------------------------------------------------------------------
// K-2: pack sc_W1 (128x128, [k][n] row-major) into MFMA B-fragment order,
// bf16 hi/lo. W1f[((ks*8+t)*64+lane)*8+j] = W1[(ks*32+(lane>>4)*8+j)*128
// + t*16+(lane&15)]. grid=8, block=256 (2048 slots).
// ---------------------------------------------------------------------------
__global__ void __launch_bounds__(256) k_castw1(
    const float* __restrict__ W1, unsigned short* __restrict__ W1fh,
    unsigned short* __restrict__ W1fl) {
  const int s = blockIdx.x * 256 + threadIdx.x;   // 0..2047
  const int lane = s & 63;
  const int t = (s >> 6) & 7;
  const int ks = s >> 9;
  const int kbase = ks * 32 + (lane >> 4) * 8;
  const int n = t * 16 + (lane & 15);
  unsigned short hv[8], lv[8];
  #pragma unroll
  for (int j = 0; j < 8; ++j) {
    float w = W1[(size_t)(kbase + j) * 128 + n];
    unsigned short h = f2bf(w);
    hv[j] = h;
    lv[j] = f2bf(w - bf2f(h));
  }
  *(uint4*)&W1fh[(size_t)s * 8] = *(uint4*)hv;
  *(uint4*)&W1fl[(size_t)s * 8] = *(uint4*)lv;
}

// ---------------------------------------------------------------------------
// K0: per-node prep, 4 nodes per block. grid=256, block=128.
// Emits hidden as bf16 hi/lo, node-major [1024][128].
// ---------------------------------------------------------------------------
__global__ void k_prep(const float* __restrict__ hf, const int* __restrict__ z,
                       const float* __restrict__ pos, const float* __restrict__ z_emb,
                       const float* __restrict__ vwW0, const float* __restrict__ vwb0,
                       const float* __restrict__ vwW1, const float* __restrict__ vwb1,
                       const float* __restrict__ scW0,
                       unsigned short* __restrict__ hTh, unsigned short* __restrict__ hTl,
                       float* __restrict__ Pn, float* __restrict__ Pa,
                       float* __restrict__ xvu, float* __restrict__ y1cw) {
  const int g0 = blockIdx.x * 4;
  const int b = g0 >> 6;
  const int t = threadIdx.x;

  __shared__ float vin[4][64];
  __shared__ float invn[4][96];
  __shared__ float h0[4][128];
  __shared__ float uS[4][3];
  __shared__ float rS[4];

  if (t < 4) {
    const int g = g0 + t;
    float px = pos[g * 3 + 0] - pos[(b * 64) * 3 + 0];
    float py = pos[g * 3 + 1] - pos[(b * 64) * 3 + 1];
    float pz = pos[g * 3 + 2] - pos[(b * 64) * 3 + 2];
    float r = sqrtf(px * px + py * py + pz * pz + 1e-12f);
    float rm = fmaxf(r, 1e-8f);
    uS[t][0] = px / rm; uS[t][1] = py / rm; uS[t][2] = pz / rm;
    rS[t] = r;
  }
  __syncthreads();

  if (t < 32) {
    const float delta = 6.0f / 31.0f;
    const float gamma = 1.0f / (delta * delta + 1e-12f);
    #pragma unroll
    for (int nn = 0; nn < 4; ++nn) {
      int zi = z[g0 + nn];
      vin[nn][t] = z_emb[zi * 32 + t];
      float rc = fminf(rS[nn], 6.0f);
      float d = rc - (float)t * delta;
      vin[nn][32 + t] = __expf(-gamma * d * d);
      float a = hf[(g0 + nn) * 160 + 64 + t * 3 + 0] * uS[nn][0]
              + hf[(g0 + nn) * 160 + 64 + t * 3 + 1] * uS[nn][1]
              + hf[(g0 + nn) * 160 + 64 + t * 3 + 2] * uS[nn][2];
      xvu[(g0 + nn) * 32 + t] = a;
    }
  }
  if (t < 96) {
    #pragma unroll
    for (int nn = 0; nn < 4; ++nn) {
      const int g = g0 + nn;
      if (t < 64) {
        invn[nn][t] = hf[g * 160 + t];
      } else {
        int o = t - 64;
        float v0 = hf[g * 160 + 64 + o * 3 + 0];
        float v1 = hf[g * 160 + 64 + o * 3 + 1];
        float v2 = hf[g * 160 + 64 + o * 3 + 2];
        invn[nn][t] = sqrtf((v0 * v0 + v1 * v1 + v2 * v2) * (1.0f / 3.0f) + 1e-8f);
      }
    }
  }
  if (t < 4) {
    const int n = (g0 + t) & 63;
    float r = rS[t];
    float cw = 0.0f;
    if (r <= 6.0f && n != 0) cw = 0.5f * (cosf(PIF * r * (1.0f / 6.0f)) + 1.0f);
    y1cw[(g0 + t) * 4 + 0] = SQRT3F * uS[t][0];
    y1cw[(g0 + t) * 4 + 1] = SQRT3F * uS[t][1];
    y1cw[(g0 + t) * 4 + 2] = SQRT3F * uS[t][2];
    y1cw[(g0 + t) * 4 + 3] = cw;
  }
  __syncthreads();

  {
    float a0 = vwb0[t], a1 = a0, a2 = a0, a3 = a0;
    #pragma unroll 8
    for (int k = 0; k < 64; ++k) {
      float w = vwW0[k * 128 + t];
      a0 = fmaf(vin[0][k], w, a0);
      a1 = fmaf(vin[1][k], w, a1);
      a2 = fmaf(vin[2][k], w, a2);
      a3 = fmaf(vin[3][k], w, a3);
    }
    h0[0][t] = silu_f(a0); h0[1][t] = silu_f(a1);
    h0[2][t] = silu_f(a2); h0[3][t] = silu_f(a3);
  }
  __syncthreads();
  {
    float a0 = vwb1[t], a1 = a0, a2 = a0, a3 = a0;
    #pragma unroll 8
    for (int k = 0; k < 128; ++k) {
      float w = vwW1[k * 128 + t];
      a0 = fmaf(h0[0][k], w, a0);
      a1 = fmaf(h0[1][k], w, a1);
      a2 = fmaf(h0[2][k], w, a2);
      a3 = fmaf(h0[3][k], w, a3);
    }
    float hv[4] = {silu_f(a0), silu_f(a1), silu_f(a2), silu_f(a3)};
    #pragma unroll
    for (int nn = 0; nn < 4; ++nn) {
      unsigned short hh = f2bf(hv[nn]);
      hTh[(size_t)(g0 + nn) * 128 + t] = hh;
      hTl[(size_t)(g0 + nn) * 128 + t] = f2bf(hv[nn] - bf2f(hh));
    }
  }
  {
    float p0 = 0.f, p1 = 0.f, p2 = 0.f, p3 = 0.f;
    #pragma unroll 8
    for (int k = 0; k < 96; ++k) {
      float w = scW0[(96 + k) * 128 + t];
      p0 = fmaf(invn[0][k], w, p0);
      p1 = fmaf(invn[1][k], w, p1);
      p2 = fmaf(invn[2][k], w, p2);
      p3 = fmaf(invn[3][k], w, p3);
    }
    #pragma unroll 8
    for (int k = 0; k < 64; ++k) {
      float w = scW0[(192 + k) * 128 + t];
      p0 = fmaf(vin[0][k], w, p0);
      p1 = fmaf(vin[1][k], w, p1);
      p2 = fmaf(vin[2][k], w, p2);
      p3 = fmaf(vin[3][k], w, p3);
    }
    Pn[(g0 + 0) * 128 + t] = p0;
    Pn[(g0 + 1) * 128 + t] = p1;
    Pn[(g0 + 2) * 128 + t] = p2;
    Pn[(g0 + 3) * 128 + t] = p3;
  }
  if ((g0 & 63) == 0) {
    float p = 0.0f;
    #pragma unroll 8
    for (int k = 0; k < 96; ++k) p = fmaf(invn[0][k], scW0[k * 128 + t], p);
    Pa[b * 128 + t] = p;
  }
}

// ---------------------------------------------------------------------------
// KPe: Pe[e][t] = sc_b0[t] + e_feat[e]@We. grid=128, block=128.
// ---------------------------------------------------------------------------
__global__ void k_pe(const float* __restrict__ e_feat, const float* __restrict__ scW0,
                     const float* __restrict__ scb0, float* __restrict__ Pe) {
  const int e = blockIdx.x;
  const int t = threadIdx.x;
  float a = scb0[t];
  #pragma unroll
  for (int k = 0; k < 16; ++k) a = fmaf(e_feat[e * 16 + k], scW0[(256 + k) * 128 + t], a);
  Pe[e * 128 + t] = a;
}

// ---------------------------------------------------------------------------
// K2 v6: MFMA bf16 (3-term hi/lo split) GEMM + fused contraction. (unchanged)
// ---------------------------------------------------------------------------
union SMemU {
  struct {
    unsigned short Ah[64][40];
    unsigned short Al[64][40];
    unsigned short Bh[256][40];
    unsigned short Bl[256][40];
  } mm;
  struct {
    float vals[64][160];
    float sv[64][32];
  } ep;
};

__global__ void __launch_bounds__(256, 3) k_tp(
    const unsigned short* __restrict__ hTh, const unsigned short* __restrict__ hTl,
    const unsigned short* __restrict__ W2Th, const unsigned short* __restrict__ W2Tl,
    const float* __restrict__ b2, const float* __restrict__ hf,
    const float* __restrict__ xvu, const float* __restrict__ y1cw,
    float* __restrict__ values) {
  const int g0 = blockIdx.x * 64;
  const int chunk = blockIdx.y;
  const int C0 = chunk * 256;
  const int tid = threadIdx.x;

  __shared__ SMemU sm;

  const int w = tid >> 6;
  const int l = tid & 63;
  const int q = l >> 4;
  const int cq = l & 15;

  const int snode = tid >> 2;
  const int sko = (tid & 3) * 8;

  v4f acc[16];
  #pragma unroll
  for (int t = 0; t < 16; ++t) acc[t] = (v4f){0.f, 0.f, 0.f, 0.f};

  for (int ks = 0; ks < 4; ++ks) {
    const int kbase = ks * 32;
    uint4 ahv = *(const uint4*)&hTh[(size_t)(g0 + snode) * 128 + kbase + sko];
    uint4 alv = *(const uint4*)&hTl[(size_t)(g0 + snode) * 128 + kbase + sko];
    uint4 bhv[4], blv[4];
    #pragma unroll
    for (int rep = 0; rep < 4; ++rep) {
      const int col = snode + 64 * rep;
      bhv[rep] = *(const uint4*)&W2Th[(size_t)(C0 + col) * 128 + kbase + sko];
      blv[rep] = *(const uint4*)&W2Tl[(size_t)(C0 + col) * 128 + kbase + sko];
    }
    __syncthreads();
    *(uint4*)&sm.mm.Ah[snode][sko] = ahv;
    *(uint4*)&sm.mm.Al[snode][sko] = alv;
    #pragma unroll
    for (int rep = 0; rep < 4; ++rep) {
      const int col = snode + 64 * rep;
      *(uint4*)&sm.mm.Bh[col][sko] = bhv[rep];
      *(uint4*)&sm.mm.Bl[col][sko] = blv[rep];
    }
    __syncthreads();

    const int m = w * 16 + cq;
    v8s ah = *(const v8s*)&sm.mm.Ah[m][q * 8];
    v8s al = *(const v8s*)&sm.mm.Al[m][q * 8];
    #pragma unroll
    for (int t = 0; t < 16; ++t) {
      v8s bh = *(const v8s*)&sm.mm.Bh[t * 16 + cq][q * 8];
      v8s bl = *(const v8s*)&sm.mm.Bl[t * 16 + cq][q * 8];
      acc[t] = __builtin_amdgcn_mfma_f32_16x16x32_bf16(ah, bh, acc[t], 0, 0, 0);
      acc[t] = __builtin_amdgcn_mfma_f32_16x16x32_bf16(al, bh, acc[t], 0, 0, 0);
      acc[t] = __builtin_amdgcn_mfma_f32_16x16x32_bf16(ah, bl, acc[t], 0, 0, 0);
    }
  }
  __syncthreads();

  for (int idx = tid; idx < 64 * 160; idx += 256) ((float*)sm.ep.vals)[idx] = 0.0f;
  for (int idx = tid; idx < 64 * 32; idx += 256) ((float*)sm.ep.sv)[idx] = 0.0f;
  __syncthreads();

  const int w16q4 = w * 16 + q * 4;

  if (chunk < 16) {
    #pragma unroll
    for (int r = 0; r < 4; ++r) {
      const int n = w16q4 + r;
      const float* hfrow = hf + (size_t)(g0 + n) * 160;
      #pragma unroll
      for (int tl = 0; tl < 4; ++tl) {
        float s = 0.f;
        #pragma unroll
        for (int th = 0; th < 4; ++th) {
          const int t = tl + 4 * th;
          float tp = acc[t][r] + b2[C0 + t * 16 + cq];
          s = fmaf(hfrow[chunk * 4 + th], tp, s);
        }
        atomicAdd(&sm.ep.vals[n][tl * 16 + cq], s);
      }
    }
  } else if (chunk < 24) {
    #pragma unroll
    for (int r = 0; r < 4; ++r) {
      const int n = w16q4 + r;
      const float* hfrow = hf + (size_t)(g0 + n) * 160;
      #pragma unroll
      for (int tl = 0; tl < 2; ++tl) {
        float s = 0.f;
        #pragma unroll
        for (int th = 0; th < 8; ++th) {
          const int t = tl + 2 * th;
          float tp = acc[t][r] + b2[C0 + t * 16 + cq];
          s = fmaf(hfrow[(chunk - 16) * 8 + th], tp, s);
        }
        atomicAdd(&sm.ep.sv[n][tl * 16 + cq], s);
      }
    }
  } else if (chunk < 28) {
    #pragma unroll
    for (int r = 0; r < 4; ++r) {
      const int n = w16q4 + r;
      const float* hfrow = hf + (size_t)(g0 + n) * 160;
      #pragma unroll
      for (int tl = 0; tl < 2; ++tl) {
        float s0 = 0.f, s1 = 0.f, s2 = 0.f;
        #pragma unroll
        for (int th = 0; th < 8; ++th) {
          const int t = tl + 2 * th;
          const int i = (chunk - 24) * 8 + th;
          float tp = acc[t][r] + b2[C0 + t * 16 + cq];
          s0 = fmaf(hfrow[64 + 3 * i + 0], tp, s0);
          s1 = fmaf(hfrow[64 + 3 * i + 1], tp, s1);
          s2 = fmaf(hfrow[64 + 3 * i + 2], tp, s2);
        }
        const int base = 64 + 3 * (tl * 16 + cq);
        atomicAdd(&sm.ep.vals[n][base + 0], s0);
        atomicAdd(&sm.ep.vals[n][base + 1], s1);
        atomicAdd(&sm.ep.vals[n][base + 2], s2);
      }
    }
  } else {
    #pragma unroll
    for (int r = 0; r < 4; ++r) {
      const int n = w16q4 + r;
      const float* xurow = xvu + (size_t)(g0 + n) * 32;
      #pragma unroll
      for (int tl = 0; tl < 4; ++tl) {
        float s = 0.f;
        #pragma unroll
        for (int th = 0; th < 4; ++th) {
          const int t = tl + 4 * th;
          float tp = acc[t][r] + b2[C0 + t * 16 + cq];
          s = fmaf(xurow[(chunk - 28) * 4 + th], tp, s);
        }
        atomicAdd(&sm.ep.vals[n][tl * 16 + cq], s);
      }
    }
  }
  __syncthreads();

  if (chunk < 16 || chunk >= 28) {
    for (int idx = tid; idx < 4096; idx += 256) {
      int n = idx >> 6, d = idx & 63;
      atomicAdd(&values[(size_t)(g0 + n) * 160 + d], ALPHAF * sm.ep.vals[n][d]);
    }
  } else if (chunk < 24) {
    for (int idx = tid; idx < 2048; idx += 256) {
      int n = idx >> 5, o = idx & 31;
      float s = ALPHAF * sm.ep.sv[n][o];
      float4 y = *(const float4*)(y1cw + (size_t)(g0 + n) * 4);
      size_t base = (size_t)(g0 + n) * 160 + 64 + 3 * o;
      atomicAdd(&values[base + 0], s * y.x);
      atomicAdd(&values[base + 1], s * y.y);
      atomicAdd(&values[base + 2], s * y.z);
    }
  } else {
    for (int idx = tid; idx < 6144; idx += 256) {
      int n = idx / 96, d = idx - n * 96;
      atomicAdd(&values[(size_t)(g0 + n) * 160 + 64 + d], ALPHAF * sm.ep.vals[n][64 + d]);
    }
  }
}

// ---------------------------------------------------------------------------
// K3 v4: MFMA gate MLP + aggregation per (b,e). grid=2048, block=256.
// A-fragments computed directly in registers (silu(Pn+Prow) -> bf16 hi/lo,
// fragment map m=lane&15, k=q*8+j — layout verified by k_tp R6 pass).
// W1 read from fragment-ordered global (k_castw1), coalesced v8s loads.
// No LDS GEMM tiles, no barriers in K-loop.
// ---------------------------------------------------------------------------
__global__ void __launch_bounds__(256, 4) k_gate_agg(
    const float* __restrict__ Pa, const float* __restrict__ Pe,
    const float* __restrict__ Pn,
    const unsigned short* __restrict__ W1fh, const unsigned short* __restrict__ W1fl,
    const float* __restrict__ b1, const float* __restrict__ W2v,
    const float* __restrict__ b2s, const float* __restrict__ y1cw,
    const float* __restrict__ values, float* __restrict__ inv_agg) {
  const int bid = blockIdx.x;
  const int b = bid >> 7, e = bid & 127;
  const int tid = threadIdx.x;

  __shared__ float Prow[128];
  __shared__ float gpre[64];
  __shared__ float gateL[64];
  __shared__ float aggL[160];
  __shared__ float normS;

  if (tid < 128) Prow[tid] = Pa[b * 128 + tid] + Pe[e * 128 + tid];
  __syncthreads();

  const int w = tid >> 6, l = tid & 63;
  const int q = l >> 4, cq = l & 15;
  const int node = w * 16 + cq;
  const float* pnrow = Pn + (size_t)(b * 64 + node) * 128;

  v4f acc[8];
  #pragma unroll
  for (int t = 0; t < 8; ++t) acc[t] = (v4f){0.f, 0.f, 0.f, 0.f};

  #pragma unroll
  for (int ks = 0; ks < 4; ++ks) {
    const int k0 = ks * 32 + q * 8;
    float4 p0 = *(const float4*)(pnrow + k0);
    float4 p1 = *(const float4*)(pnrow + k0 + 4);
    float4 r0 = *(const float4*)(&Prow[k0]);
    float4 r1 = *(const float4*)(&Prow[k0 + 4]);
    float xv[8] = {p0.x + r0.x, p0.y + r0.y, p0.z + r0.z, p0.w + r0.w,
                   p1.x + r1.x, p1.y + r1.y, p1.z + r1.z, p1.w + r1.w};
    v8s avh, avl;
    #pragma unroll
    for (int j = 0; j < 8; ++j) {
      float x = silu_f(xv[j]);
      unsigned short h = f2bf(x);
      avh[j] = (short)h;
      avl[j] = (short)f2bf(x - bf2f(h));
    }
    #pragma unroll
    for (int t = 0; t < 8; ++t) {
      const size_t fb = (size_t)((ks * 8 + t) * 64 + l) * 8;
      v8s bh = *(const v8s*)&W1fh[fb];
      v8s bl = *(const v8s*)&W1fl[fb];
      acc[t] = __builtin_amdgcn_mfma_f32_16x16x32_bf16(avh, bh, acc[t], 0, 0, 0);
      acc[t] = __builtin_amdgcn_mfma_f32_16x16x32_bf16(avl, bh, acc[t], 0, 0, 0);
      acc[t] = __builtin_amdgcn_mfma_f32_16x16x32_bf16(avh, bl, acc[t], 0, 0, 0);
    }
  }

  // epilogue: h2 = silu(h1 + b1), partial dot with W2 column, reduce over cq.
  float part0 = 0.f, part1 = 0.f, part2 = 0.f, part3 = 0.f;
  #pragma unroll
  for (int t = 0; t < 8; ++t) {
    float bb = b1[t * 16 + cq];
    float wg = W2v[t * 16 + cq];
    part0 = fmaf(silu_f(acc[t][0] + bb), wg, part0);
    part1 = fmaf(silu_f(acc[t][1] + bb), wg, part1);
    part2 = fmaf(silu_f(acc[t][2] + bb), wg, part2);
    part3 = fmaf(silu_f(acc[t][3] + bb), wg, part3);
  }
  #pragma unroll
  for (int off = 1; off < 16; off <<= 1) {
    part0 += __shfl_xor(part0, off);
    part1 += __shfl_xor(part1, off);
    part2 += __shfl_xor(part2, off);
    part3 += __shfl_xor(part3, off);
  }
  if (cq == 0) {
    gpre[w * 16 + q * 4 + 0] = part0;
    gpre[w * 16 + q * 4 + 1] = part1;
    gpre[w * 16 + q * 4 + 2] = part2;
    gpre[w * 16 + q * 4 + 3] = part3;
  }
  __syncthreads();

  if (tid < 64) {
    float gv = sigmoid_f(gpre[tid] + b2s[0]);
    gv *= y1cw[(b * 64 + tid) * 4 + 3];
    gateL[tid] = gv;
    float t2 = gv;
    #pragma unroll
    for (int off = 32; off > 0; off >>= 1) t2 += __shfl_down(t2, off);
    if (tid == 0) normS = fmaxf(t2, 1e-8f);
  }
  __syncthreads();

  if (tid < 160) {
    float a = 0.0f;
    const float* vp = values + (size_t)b * 64 * 160 + tid;
    #pragma unroll 4
    for (int n = 0; n < 64; ++n) a = fmaf(gateL[n], vp[n * 160], a);
    aggL[tid] = a / normS;
  }
  __syncthreads();
  if (tid < 96) {
    float rv;
    if (tid < 64) {
      rv = aggL[tid];
    } else {
      int o = tid - 64;
      float a0 = aggL[64 + o * 3 + 0];
      float a1 = aggL[64 + o * 3 + 1];
      float a2 = aggL[64 + o * 3 + 2];
      rv = sqrtf((a0 * a0 + a1 * a1 + a2 * a2) * (1.0f / 3.0f) + 1e-8f);
    }
    inv_agg[bid * 96 + tid] = rv;
  }
}

// ---------------------------------------------------------------------------
// K4: MLP layer Y = act(X@W + b). 32-row tiles -> 64 blocks. K in {96,128}.
// ---------------------------------------------------------------------------
__global__ void __launch_bounds__(256) k_mlp(
    const float* __restrict__ X, const float* __restrict__ W,
    const float* __restrict__ bias, float* __restrict__ Y,
    int K, int act) {
  const int r0 = blockIdx.x * 32;
  const int tid = threadIdx.x;

  __shared__ float A[32][129];

  for (int idx = tid; idx < 32 * K; idx += 256) {
    int n = idx / K, k = idx - n * K;
    A[n][k] = X[(size_t)(r0 + n) * K + k];
  }
  __syncthreads();

  const int rowg = tid >> 4, colg = tid & 15;
  const int r2 = rowg * 2, c8 = colg * 8;

  float acc[2][8];
  #pragma unroll
  for (int i = 0; i < 2; ++i)
    #pragma unroll
    for (int jj = 0; jj < 8; ++jj) acc[i][jj] = 0.0f;

  const float* wptr = W + c8;
  #pragma unroll 4
  for (int k = 0; k < K; ++k) {
    float4 w0 = *(const float4*)(wptr + k * 128);
    float4 w1v = *(const float4*)(wptr + k * 128 + 4);
    float av0 = A[r2 + 0][k];
    float av1 = A[r2 + 1][k];
    float wv[8] = {w0.x, w0.y, w0.z, w0.w, w1v.x, w1v.y, w1v.z, w1v.w};
    #pragma unroll
    for (int jj = 0; jj < 8; ++jj) {
      acc[0][jj] = fmaf(av0, wv[jj], acc[0][jj]);
      acc[1][jj] = fmaf(av1, wv[jj], acc[1][jj]);
    }
  }

  #pragma unroll
  for (int jj = 0; jj < 8; ++jj) {
    float bb = bias[c8 + jj];
    #pragma unroll
    for (int i = 0; i < 2; ++i) {
      float v = acc[i][jj] + bb;
      if (act) v = silu_f(v);
      Y[(size_t)(r0 + r2 + i) * 128 + c8 + jj] = v;
    }
  }
}

// ---------------------------------------------------------------------------
extern "C" void kernel_launch(void* const* d_in, const int* in_sizes, int n_in,
                              void* d_out, int out_size, void* d_ws, size_t ws_size,
                              hipStream_t stream) {
  const float* hf    = (const float*)d_in[0];
  const int*   z     = (const int*)  d_in[1];
  const float* pos   = (const float*)d_in[2];
  const float* e_feat= (const float*)d_in[4];
  const float* z_emb = (const float*)d_in[5];
  const float* vwW0  = (const float*)d_in[6];
  const float* vwb0  = (const float*)d_in[7];
  const float* vwW1  = (const float*)d_in[8];
  const float* vwb1  = (const float*)d_in[9];
  const float* vwW2  = (const float*)d_in[10];
  const float* vwb2  = (const float*)d_in[11];
  const float* scW0  = (const float*)d_in[12];
  const float* scb0  = (const float*)d_in[13];
  const float* scW1  = (const float*)d_in[14];
  const float* scb1  = (const float*)d_in[15];
  const float* scW2  = (const float*)d_in[16];
  const float* scb2  = (const float*)d_in[17];
  const float* oW0   = (const float*)d_in[18];
  const float* ob0   = (const float*)d_in[19];
  const float* oW1   = (const float*)d_in[20];
  const float* ob1   = (const float*)d_in[21];
  const float* oW2   = (const float*)d_in[22];
  const float* ob2   = (const float*)d_in[23];
  float* out = (float*)d_out;

  float* ws = (float*)d_ws;
  unsigned short* W2Th = (unsigned short*)(ws);            // 589824 fl
  unsigned short* W2Tl = (unsigned short*)(ws + 589824);   // 589824 fl
  unsigned short* hTh  = (unsigned short*)(ws + 1179648);  // 65536 fl
  unsigned short* hTl  = (unsigned short*)(ws + 1245184);  // 65536 fl
  float* Pn     = ws + 1310720;   // 131072
  float* Pa     = Pn + 131072;    // 2048
  float* Pe     = Pa + 2048;      // 16384
  float* xvu    = Pe + 16384;     // 32768
  float* y1cw   = xvu + 32768;    // 4096
  float* values = y1cw + 4096;    // 163840
  float* invagg = values + 163840;// 196608
  unsigned short* W1fh = (unsigned short*)(invagg + 196608);  // 8192 fl
  unsigned short* W1fl = (unsigned short*)(invagg + 196608 + 8192);
  // H1/H2 alias the W2T region (dead after k_tp)
  float* H1     = ws;             // 262144
  float* H2     = ws + 262144;    // 262144

  hipMemsetAsync(values, 0, 163840 * sizeof(float), stream);

  k_castw2<<<144, 256, 0, stream>>>(vwW2, W2Th, W2Tl);
  k_castw1<<<8, 256, 0, stream>>>(scW1, W1fh, W1fl);
  k_prep<<<256, 128, 0, stream>>>(hf, z, pos, z_emb, vwW0, vwb0, vwW1, vwb1,
                                  scW0, hTh, hTl, Pn, Pa, xvu, y1cw);
  k_pe<<<128, 128, 0, stream>>>(e_feat, scW0, scb0, Pe);
  k_tp<<<dim3(16, 36), 256, 0, stream>>>(hTh, hTl, W2Th, W2Tl, vwb2, hf, xvu,
                                         y1cw, values);
  k_gate_agg<<<2048, 256, 0, stream>>>(Pa, Pe, Pn, W1fh, W1fl, scb1, scW2, scb2,
                                       y1cw, values, invagg);
  k_mlp<<<64, 256, 0, stream>>>(invagg, oW0, ob0, H1, 96, 1);
  k_mlp<<<64, 256, 0, stream>>>(H1, oW1, ob1, H2, 128, 1);
  k_mlp<<<64, 256, 0, stream>>>(H2, oW2, ob2, out, 128, 0);
}